// Round 1
// 450.286 us; speedup vs baseline: 1.0631x; 1.0631x over previous
//
#include <hip/hip_runtime.h>
#include <hip/hip_bf16.h>
#include <math.h>

#define DIN 20
#define C 128
#define HC 256
#define EB1 8192
#define EB2 4096
#define MAXNB 400

typedef unsigned short u16;
typedef unsigned int u32;
typedef unsigned long long u64;
typedef __bf16 bf16x8 __attribute__((ext_vector_type(8)));
typedef float f32x4 __attribute__((ext_vector_type(4)));

__device__ __forceinline__ float bfbits2f(unsigned int lo16) {
    return __uint_as_float(lo16 << 16);
}
__device__ __forceinline__ u16 f2bf_rne(float f) {
    unsigned int b = __float_as_uint(f);
    return (u16)((b + 0x7FFFu + ((b >> 16) & 1u)) >> 16);
}

// exclusive scan of cnt[0..511] -> off[0..511] using 256 threads; tmp[256]
__device__ __forceinline__ void scan512(u32* cnt, u32* off, u32* tmp) {
    int t = threadIdx.x;
    u32 a = cnt[2 * t], b = cnt[2 * t + 1];
    u32 s = a + b;
    tmp[t] = s;
    __syncthreads();
    for (int o = 1; o < 256; o <<= 1) {
        u32 v = (t >= o) ? tmp[t - o] : 0u;
        __syncthreads();
        tmp[t] += v;
        __syncthreads();
    }
    u32 excl = tmp[t] - s;
    off[2 * t] = excl;
    off[2 * t + 1] = excl + a;
    __syncthreads();
}

// ---------------- K1: BN stats (second moment 20x20 + column sums) ----------------
__global__ __launch_bounds__(256) void k_stats(const float* __restrict__ x, int NR,
                                               float* __restrict__ stats)
{
    __shared__ float L[256][DIN];
    int t = threadIdx.x;
    int r = blockIdx.x * 256 + t;
    if (r < NR) {
        #pragma unroll
        for (int k = 0; k < DIN; k++) L[t][k] = x[r * DIN + k];
    } else {
        #pragma unroll
        for (int k = 0; k < DIN; k++) L[t][k] = 0.f;
    }
    __syncthreads();
    if (t < 210) {
        int p = 0, q = t;
        while (q >= DIN - p) { q -= (DIN - p); p++; }
        q += p;
        float acc = 0.f;
        for (int rr = 0; rr < 256; rr++) acc += L[rr][p] * L[rr][q];
        atomicAdd(&stats[p * DIN + q], acc);
        if (p != q) atomicAdd(&stats[q * DIN + p], acc);
    } else if (t < 230) {
        int k = t - 210;
        float acc = 0.f;
        for (int rr = 0; rr < 256; rr++) acc += L[rr][k];
        atomicAdd(&stats[400 + k], acc);
    }
}

// ---------------- K2: fold BN; vd1/vd2; u1/u2; T; cb; + fused B-pack --------------
// stats: [420..547]=BN scale, [548..675]=BN shift, [676..931]=vd1[k*2+h],
//        [932..1187]=vd2[c*2+h'], [1188..1189]=cb[h'],
//        [1200..1455]=u1[k*2+h], [1456..1711]=u2[k*2+h], [1712..2223]=T[k*4+h*2+h']
// block 0: precomp; blocks 1..32: pack g2_ws -> bf16 MFMA B-fragment layout
__global__ __launch_bounds__(256) void k_precomp_pack(float* __restrict__ stats,
    const float* __restrict__ W,
    const float* __restrict__ gamma, const float* __restrict__ beta,
    const float* __restrict__ g1_wd, const float* __restrict__ g1_ad,
    const float* __restrict__ g2_wd, const float* __restrict__ g2_ad,
    const float* __restrict__ g1_ws, const float* __restrict__ g1_as,
    const float* __restrict__ g2_ws, const float* __restrict__ g2_as,
    const float* __restrict__ g1b, float invN, u16* __restrict__ wsp)
{
    int t = threadIdx.x;
    if (blockIdx.x > 0) {
        // ---- pack part (former k_pack) ----
        int idx0 = ((blockIdx.x - 1) * 256 + t) * 4;
        #pragma unroll
        for (int i = 0; i < 4; i++) {
            int flat = idx0 + i;           // [nt(16)][kb(4)][lane(64)][j(8)]
            int j = flat & 7;
            int lane = (flat >> 3) & 63;
            int kb = (flat >> 9) & 3;
            int nt = flat >> 11;
            int k = kb * 32 + (lane >> 4) * 8 + j;
            int n = nt * 16 + (lane & 15);
            wsp[flat] = f2bf_rne(g2_ws[k * HC + n]);
        }
        return;
    }
    __shared__ float Sm[420];
    __shared__ float vd2s[256];
    for (int i = t; i < 420; i += 256) Sm[i] = stats[i];
    __syncthreads();
    if (t < C) {
        float w[DIN];
        #pragma unroll
        for (int k = 0; k < DIN; k++) w[k] = W[k * C + t];
        float mb = 0.f;
        #pragma unroll
        for (int k = 0; k < DIN; k++) mb += Sm[400 + k] * invN * w[k];
        float e2 = 0.f;
        for (int p = 0; p < DIN; p++) {
            float acc2 = 0.f;
            #pragma unroll
            for (int q = 0; q < DIN; q++) acc2 += Sm[p * DIN + q] * w[q];
            e2 += w[p] * acc2;
        }
        e2 *= invN;
        float var = e2 - mb * mb;
        float s = gamma[t] * rsqrtf(var + 1e-5f);
        stats[420 + t] = s;
        stats[548 + t] = beta[t] - s * mb;   // b_rl cancels inside BN
    }
    {
        int k = t >> 1, h = t & 1;
        const float4* wd1 = (const float4*)(g1_wd + k * HC + h * C);
        const float4* wd2 = (const float4*)(g2_wd + k * HC + h * C);
        const float4* ws1 = (const float4*)(g1_ws + k * HC + h * C);
        const float4* ws2 = (const float4*)(g2_ws + k * HC + h * C);
        const float4* ad1 = (const float4*)(g1_ad + h * C);
        const float4* ad2 = (const float4*)(g2_ad + h * C);
        const float4* as1 = (const float4*)(g1_as + h * C);
        const float4* as2 = (const float4*)(g2_as + h * C);
        float a1 = 0.f, a2 = 0.f, s1 = 0.f, s2 = 0.f;
        #pragma unroll 4
        for (int q = 0; q < 32; q++) {
            float4 x, y;
            x = wd1[q]; y = ad1[q];
            a1 += x.x * y.x + x.y * y.y + x.z * y.z + x.w * y.w;
            x = wd2[q]; y = ad2[q];
            a2 += x.x * y.x + x.y * y.y + x.z * y.z + x.w * y.w;
            x = ws1[q]; y = as1[q];
            s1 += x.x * y.x + x.y * y.y + x.z * y.z + x.w * y.w;
            x = ws2[q]; y = as2[q];
            s2 += x.x * y.x + x.y * y.y + x.z * y.z + x.w * y.w;
        }
        stats[676 + t] = a1;
        stats[932 + t] = a2;
        stats[1200 + t] = s1;
        stats[1456 + t] = s2;
        vd2s[t] = a2;
    }
    __syncthreads();
    {
        int k = t >> 1, h = t & 1;
        const float4* ws1p = (const float4*)(g1_ws + k * HC + h * C);
        float t0 = 0.f, t1 = 0.f;
        #pragma unroll 4
        for (int q = 0; q < 32; q++) {
            float4 wv = ws1p[q];
            int c = q * 4;
            t0 += wv.x * vd2s[(c + 0) * 2 + 0] + wv.y * vd2s[(c + 1) * 2 + 0]
                + wv.z * vd2s[(c + 2) * 2 + 0] + wv.w * vd2s[(c + 3) * 2 + 0];
            t1 += wv.x * vd2s[(c + 0) * 2 + 1] + wv.y * vd2s[(c + 1) * 2 + 1]
                + wv.z * vd2s[(c + 2) * 2 + 1] + wv.w * vd2s[(c + 3) * 2 + 1];
        }
        stats[1712 + t * 2 + 0] = t0;
        stats[1712 + t * 2 + 1] = t1;
    }
    if (t < 2) {
        float cb = 0.f;
        for (int k = 0; k < C; k++) cb += g1b[k] * vd2s[k * 2 + t];
        stats[1188 + t] = cb;
    }
}

// ---------------- K3: BN(x@W) folded -> a_d1 = r0.vd1, advd = r0.vd2 --------------
__global__ __launch_bounds__(256) void k_r0(const float* __restrict__ x, const float* __restrict__ W,
    const float* __restrict__ stats, int NR,
    float* __restrict__ a_d, float* __restrict__ advd)
{
    __shared__ float xr[16 * DIN];
    __shared__ float red[16];
    int t = threadIdx.x;
    int rowBase = blockIdx.x * 16;
    for (int i = t; i < 16 * DIN; i += 256) {
        int gi = rowBase * DIN + i;
        xr[i] = (gi < NR * DIN) ? x[gi] : 0.f;
    }
    int c = t & 127;
    int half = t >> 7;
    int wv = t >> 6;
    float w[DIN];
    #pragma unroll
    for (int k = 0; k < DIN; k++) w[k] = W[k * C + c];
    float s  = stats[420 + c], sh = stats[548 + c];
    float v10 = stats[676 + c * 2 + 0], v11 = stats[676 + c * 2 + 1];
    float v20 = stats[932 + c * 2 + 0], v21 = stats[932 + c * 2 + 1];
    __syncthreads();
    for (int p = 0; p < 8; p++) {
        int lr = 2 * p + half;
        float dot = 0.f;
        #pragma unroll
        for (int k = 0; k < DIN; k++) dot += w[k] * xr[lr * DIN + k];
        float val = s * dot + sh;
        float p0 = val * v10, p1 = val * v11, q0 = val * v20, q1 = val * v21;
        #pragma unroll
        for (int o = 32; o; o >>= 1) {
            p0 += __shfl_down(p0, o); p1 += __shfl_down(p1, o);
            q0 += __shfl_down(q0, o); q1 += __shfl_down(q1, o);
        }
        if ((t & 63) == 0) {
            red[wv * 4 + 0] = p0; red[wv * 4 + 1] = p1;
            red[wv * 4 + 2] = q0; red[wv * 4 + 3] = q1;
        }
        __syncthreads();
        int rowA = rowBase + 2 * p, rowB = rowA + 1;
        if (t == 0 && rowA < NR) {
            a_d[rowA * 2 + 0]  = red[0] + red[4];
            a_d[rowA * 2 + 1]  = red[1] + red[5];
            advd[rowA * 2 + 0] = red[2] + red[6];
            advd[rowA * 2 + 1] = red[3] + red[7];
        }
        if (t == 128 && rowB < NR) {
            a_d[rowB * 2 + 0]  = red[8]  + red[12];
            a_d[rowB * 2 + 1]  = red[9]  + red[13];
            advd[rowB * 2 + 0] = red[10] + red[14];
            advd[rowB * 2 + 1] = red[11] + red[15];
        }
        __syncthreads();
    }
}

// ---------------- K_ing: ingredient path = pure gather + 6 dots per row -----------
__global__ __launch_bounds__(256) void k_ing(const float* __restrict__ table,
    const int* __restrict__ ids, const float* __restrict__ stats,
    int Ns, float* __restrict__ a_s, float* __restrict__ psi)
{
    __shared__ float u1s[256];
    __shared__ float Ts[512];
    int t = threadIdx.x;
    u1s[t] = stats[1200 + t];
    Ts[t] = stats[1712 + t];
    Ts[256 + t] = stats[1968 + t];
    __syncthreads();
    int r = t >> 3, cg = t & 7;
    int row = blockIdx.x * 32 + r;
    float as0 = 0.f, as1 = 0.f, p00 = 0.f, p01 = 0.f, p10 = 0.f, p11 = 0.f;
    if (row < Ns) {
        const float* xp = table + (size_t)ids[row] * C + cg * 16;
        #pragma unroll
        for (int q = 0; q < 4; q++) {
            float4 v = ((const float4*)xp)[q];
            float xv[4] = {v.x, v.y, v.z, v.w};
            #pragma unroll
            for (int jj = 0; jj < 4; jj++) {
                int k = cg * 16 + q * 4 + jj;
                float xx = xv[jj];
                as0 += xx * u1s[k * 2 + 0];
                as1 += xx * u1s[k * 2 + 1];
                p00 += xx * Ts[k * 4 + 0];
                p01 += xx * Ts[k * 4 + 1];
                p10 += xx * Ts[k * 4 + 2];
                p11 += xx * Ts[k * 4 + 3];
            }
        }
    }
    #pragma unroll
    for (int m = 1; m <= 4; m <<= 1) {
        as0 += __shfl_xor(as0, m); as1 += __shfl_xor(as1, m);
        p00 += __shfl_xor(p00, m); p01 += __shfl_xor(p01, m);
        p10 += __shfl_xor(p10, m); p11 += __shfl_xor(p11, m);
    }
    if (cg == 0 && row < Ns) {
        ((float2*)a_s)[row] = make_float2(as0, as1);
        float4 pv; pv.x = p00; pv.y = p01; pv.z = p10; pv.w = p11;
        ((float4*)psi)[row] = pv;
    }
}

// ---------------- K_hs_mfma: user hs GEMM via MFMA + a_s via u2 -------------------
__global__ __launch_bounds__(256) void k_hs_mfma(const float* __restrict__ table,
    const int* __restrict__ ids, const u16* __restrict__ wsp,
    const float* __restrict__ stats, int Ns,
    u16* __restrict__ hs16, float* __restrict__ a_s)
{
    __shared__ __align__(16) u16 A[32 * 136];
    __shared__ float u2s[256];
    int t = threadIdx.x;
    u2s[t] = stats[1456 + t];
    int rowBase = blockIdx.x * 32;
    int r = t >> 3, cg = t & 7;
    int row = rowBase + r;
    float xv[16];
    if (row < Ns) {
        const float* xp = table + (size_t)ids[row] * C + cg * 16;
        #pragma unroll
        for (int q = 0; q < 4; q++) {
            float4 v = ((const float4*)xp)[q];
            xv[q * 4 + 0] = v.x; xv[q * 4 + 1] = v.y;
            xv[q * 4 + 2] = v.z; xv[q * 4 + 3] = v.w;
        }
    } else {
        #pragma unroll
        for (int q = 0; q < 16; q++) xv[q] = 0.f;
    }
    float ss = 0.f;
    #pragma unroll
    for (int q = 0; q < 16; q++) ss += xv[q] * xv[q];
    #pragma unroll
    for (int m = 1; m <= 4; m <<= 1) ss += __shfl_xor(ss, m);
    float nn = sqrtf(ss);
    float f = (nn > 1.f) ? 1.f / (nn + 1e-7f) : 1.f;
    float as0 = 0.f, as1 = 0.f;
    #pragma unroll
    for (int q = 0; q < 16; q++) {
        xv[q] *= f;
        int k = cg * 16 + q;
        as0 += xv[q] * u2s[k * 2 + 0];
        as1 += xv[q] * u2s[k * 2 + 1];
    }
    #pragma unroll
    for (int m = 1; m <= 4; m <<= 1) {
        as0 += __shfl_xor(as0, m); as1 += __shfl_xor(as1, m);
    }
    if (cg == 0 && row < Ns) ((float2*)a_s)[row] = make_float2(as0, as1);
    {
        union { u16 h[16]; uint4 u4[2]; } pk;
        #pragma unroll
        for (int q = 0; q < 16; q++) pk.h[q] = f2bf_rne(xv[q]);
        uint4* dst = (uint4*)&A[r * 136 + cg * 16];
        dst[0] = pk.u4[0];
        dst[1] = pk.u4[1];
    }
    __syncthreads();
    int w = t >> 6, l = t & 63;
    int m15 = l & 15, q4 = l >> 4;
    bf16x8 afrag[2][4];
    #pragma unroll
    for (int mt = 0; mt < 2; mt++)
        #pragma unroll
        for (int kb = 0; kb < 4; kb++)
            afrag[mt][kb] = *(const bf16x8*)&A[(mt * 16 + m15) * 136 + kb * 32 + q4 * 8];
    f32x4 acc[2][4];
    #pragma unroll
    for (int mt = 0; mt < 2; mt++)
        #pragma unroll
        for (int i = 0; i < 4; i++) acc[mt][i] = (f32x4){0.f, 0.f, 0.f, 0.f};
    #pragma unroll
    for (int kb = 0; kb < 4; kb++) {
        #pragma unroll
        for (int i = 0; i < 4; i++) {
            int nt = w * 4 + i;
            bf16x8 bfrag = *(const bf16x8*)&wsp[((nt * 4 + kb) * 64 + l) * 8];
            acc[0][i] = __builtin_amdgcn_mfma_f32_16x16x32_bf16(afrag[0][kb], bfrag, acc[0][i], 0, 0, 0);
            acc[1][i] = __builtin_amdgcn_mfma_f32_16x16x32_bf16(afrag[1][kb], bfrag, acc[1][i], 0, 0, 0);
        }
    }
    #pragma unroll
    for (int mt = 0; mt < 2; mt++) {
        #pragma unroll
        for (int i = 0; i < 4; i++) {
            int col = (w * 4 + i) * 16 + m15;
            #pragma unroll
            for (int rr = 0; rr < 4; rr++) {
                int rw = rowBase + mt * 16 + q4 * 4 + rr;
                if (rw < Ns) hs16[(size_t)rw * HC + col] = f2bf_rne(acc[mt][i][rr]);
            }
        }
    }
}

// ================= Bucketed CSR build =================
// key space [0, 2*NR): graph1 key=d, graph2 key=NR+d. bucket = key>>9.

__device__ __forceinline__ void edge_at(int i, const int* s1, const int* d1,
    const int* s2, const int* d2, int E1, int T1, int E2, int NR,
    int& s, int& key)
{
    if (i < T1) {
        if (i < E1) { s = s1[i]; key = d1[i]; }
        else        { s = i - E1; key = i - E1; }
    } else {
        int k = i - T1;
        if (k < E2) { s = s2[k]; key = NR + d2[k]; }
        else        { s = k - E2; key = NR + (k - E2); }
    }
}

// A1: per-block LDS bucket histogram -> global bucketCnt
__global__ __launch_bounds__(256) void kA1(const int* __restrict__ src1, const int* __restrict__ dst1,
    const int* __restrict__ src2, const int* __restrict__ dst2,
    int E1, int L1, int E2, int L2, int NR, int NB, u32* __restrict__ bucketCnt)
{
    __shared__ u32 cnt[MAXNB];
    int t = threadIdx.x;
    for (int i = t; i < NB; i += 256) cnt[i] = 0;
    __syncthreads();
    int T1 = E1 + L1, T = T1 + E2 + L2;
    int base = blockIdx.x * EB1;
    int nE = T - base; if (nE > EB1) nE = EB1;
    for (int j = t; j < nE; j += 256) {
        int s, key;
        edge_at(base + j, src1, dst1, src2, dst2, E1, T1, E2, NR, s, key);
        atomicAdd(&cnt[key >> 9], 1u);
    }
    __syncthreads();
    for (int b = t; b < NB; b += 256) {
        u32 c = cnt[b];
        if (c) atomicAdd(&bucketCnt[b], c);
    }
}

// scanB: PARALLEL scan over NB buckets -> bucketBase, gcur; off[n2] = Etot
__global__ __launch_bounds__(256) void kScanB(const u32* __restrict__ bucketCnt, int NB, int n2,
                       u32* __restrict__ bucketBase, u32* __restrict__ gcur,
                       int* __restrict__ off)
{
    __shared__ u32 cnt[512], offL[512], tmp[256];
    int t = threadIdx.x;
    for (int i = t; i < 512; i += 256) cnt[i] = (i < NB) ? bucketCnt[i] : 0u;
    __syncthreads();
    scan512(cnt, offL, tmp);
    for (int i = t; i < NB; i += 256) {
        u32 v = offL[i];
        bucketBase[i] = v;
        gcur[i] = v;
    }
    if (t == 0) {
        u32 total = offL[511] + cnt[511];
        bucketBase[NB] = total;
        off[n2] = (int)total;
    }
}

// A2: local counting sort by bucket, contiguous run writes of packed (key,src)
__global__ __launch_bounds__(256) void kA2(const int* __restrict__ src1, const int* __restrict__ dst1,
    const int* __restrict__ src2, const int* __restrict__ dst2,
    int E1, int L1, int E2, int L2, int NR, int NB,
    u32* __restrict__ gcur, u64* __restrict__ pairs)
{
    __shared__ u64 ldsE[EB2];
    __shared__ u64 ldsS[EB2];
    __shared__ u32 cntA[512], cntB[512], offL[512], tmp[256];
    __shared__ u32 gbase[MAXNB];
    int t = threadIdx.x;
    for (int i = t; i < 512; i += 256) { cntA[i] = 0; cntB[i] = 0; }
    __syncthreads();
    int T1 = E1 + L1, T = T1 + E2 + L2;
    int base = blockIdx.x * EB2;
    int nE = T - base; if (nE > EB2) nE = EB2;
    for (int j = t; j < nE; j += 256) {
        int s, key;
        edge_at(base + j, src1, dst1, src2, dst2, E1, T1, E2, NR, s, key);
        ldsE[j] = ((u64)(u32)key << 32) | (u32)s;
        atomicAdd(&cntA[key >> 9], 1u);
    }
    __syncthreads();
    scan512(cntA, offL, tmp);
    for (int b = t; b < NB; b += 256) {
        u32 c = cntA[b];
        gbase[b] = c ? atomicAdd(&gcur[b], c) : 0u;
    }
    __syncthreads();
    for (int j = t; j < nE; j += 256) {
        u64 e = ldsE[j];
        u32 b = ((u32)(e >> 32)) >> 9;
        u32 r = atomicAdd(&cntB[b], 1u);
        ldsS[offL[b] + r] = e;
    }
    __syncthreads();
    for (int j = t; j < nE; j += 256) {
        u64 e = ldsS[j];
        u32 b = ((u32)(e >> 32)) >> 9;
        pairs[gbase[b] + ((u32)j - offL[b])] = e;
    }
}

// B: per-bucket fine sort -> off[] + sorted[] (sequential writes)
__global__ __launch_bounds__(256) void kB(const u64* __restrict__ pairs,
    const u32* __restrict__ bucketBase, int n2,
    int* __restrict__ off, int* __restrict__ sorted)
{
    __shared__ u32 cntA[512], cntB[512], offL[512], tmp[256];
    __shared__ u32 ldsS[8192];
    int b = blockIdx.x;
    int t = threadIdx.x;
    u32 beg = bucketBase[b], end = bucketBase[b + 1];
    int dstBase = b << 9;
    for (int i = t; i < 512; i += 256) { cntA[i] = 0; cntB[i] = 0; }
    __syncthreads();
    for (u32 j = beg + t; j < end; j += 256) {
        u32 key = (u32)(pairs[j] >> 32);
        atomicAdd(&cntA[key - dstBase], 1u);
    }
    __syncthreads();
    scan512(cntA, offL, tmp);
    for (int d = t; d < 512; d += 256) {
        int gk = dstBase + d;
        if (gk < n2) off[gk] = (int)(beg + offL[d]);
    }
    u32 cnt = end - beg;
    bool fast = cnt <= 8192u;
    __syncthreads();
    for (u32 j = beg + t; j < end; j += 256) {
        u64 e = pairs[j];
        u32 d = (u32)(e >> 32) - dstBase;
        u32 r = atomicAdd(&cntB[d], 1u);
        u32 pos = offL[d] + r;
        if (fast) ldsS[pos] = (u32)e;
        else sorted[beg + pos] = (int)(u32)e;
    }
    __syncthreads();
    if (fast) {
        for (u32 j = t; j < cnt; j += 256) sorted[beg + j] = (int)ldsS[j];
    }
}

// ---------------- GAT1 agg: 16B-per-edge psi aggregation (wave per dst) -----------
__global__ __launch_bounds__(256) void k_agg_lin(const int* __restrict__ off, const int* __restrict__ sorted,
    const float* __restrict__ a_s, const float* __restrict__ psi,
    const float* __restrict__ a_d, const float* __restrict__ advd,
    const float* __restrict__ cb, int NR, float* __restrict__ a_d_out)
{
    int wave = threadIdx.x >> 6, lane = threadIdx.x & 63;
    int d = blockIdx.x * 4 + wave;
    if (d >= NR) return;
    int beg = off[d], end = off[d + 1];
    float ad0 = a_d[d * 2 + 0], ad1 = a_d[d * 2 + 1];
    float w0s = 0.f, w1s = 0.f, a00 = 0.f, a01 = 0.f, a10 = 0.f, a11 = 0.f;
    for (int j = beg + lane; j < end; j += 64) {
        int s = sorted[j];
        float2 as = ((const float2*)a_s)[s];
        float e0 = as.x + ad0; e0 = (e0 >= 0.f) ? e0 : 0.2f * e0;
        float e1 = as.y + ad1; e1 = (e1 >= 0.f) ? e1 : 0.2f * e1;
        float x0 = __expf(e0), x1 = __expf(e1);
        float4 p = ((const float4*)psi)[s];
        w0s += x0; w1s += x1;
        a00 += x0 * p.x; a01 += x0 * p.y;
        a10 += x1 * p.z; a11 += x1 * p.w;
    }
    #pragma unroll
    for (int o = 32; o; o >>= 1) {
        w0s += __shfl_down(w0s, o); w1s += __shfl_down(w1s, o);
        a00 += __shfl_down(a00, o); a01 += __shfl_down(a01, o);
        a10 += __shfl_down(a10, o); a11 += __shfl_down(a11, o);
    }
    if (lane == 0) {
        float inv0 = 1.f / (w0s + 1e-16f), inv1 = 1.f / (w1s + 1e-16f);
        a_d_out[d * 2 + 0] = advd[d * 2 + 0] + cb[0] + 0.5f * (a00 * inv0 + a10 * inv1);
        a_d_out[d * 2 + 1] = advd[d * 2 + 1] + cb[1] + 0.5f * (a01 * inv0 + a11 * inv1);
    }
}

// ---------------- GAT2 agg: fused single-pass bf16 gather (wave per dst) ----------
// 4 edges in flight per wave (16 lanes/edge); each lane loads BOTH head slices
// (2 x 16B) and keeps per-head accumulators -> 2x memory parallelism vs 2-slot,
// head-mean is register-local, ~40 VGPR gives the scheduler pipelining room.
__global__ __launch_bounds__(256) void k_agg_gather(const int* __restrict__ off, const int* __restrict__ sorted,
    const float* __restrict__ a_s, const float* __restrict__ a_d,
    const u16* __restrict__ hs16, const float* __restrict__ bias,
    int NR, float* __restrict__ out)
{
    int wave = threadIdx.x >> 6, lane = threadIdx.x & 63;
    int d = blockIdx.x * 4 + wave;
    if (d >= NR) return;
    int beg = off[d], end = off[d + 1];
    int slot = lane >> 4;      // which of 4 concurrent edges
    int cg = lane & 15;        // channel group: 8 channels per head
    float ad0 = a_d[d * 2 + 0], ad1 = a_d[d * 2 + 1];
    float w0sum = 0.f, w1sum = 0.f;
    float acc0[8], acc1[8];
    #pragma unroll
    for (int k = 0; k < 8; k++) { acc0[k] = 0.f; acc1[k] = 0.f; }

    for (int base = beg; base < end; base += 64) {
        int rem = end - base; if (rem > 64) rem = 64;
        int pidx = base + ((lane < rem) ? lane : (rem - 1));
        int sp = sorted[pidx];
        float2 ap = ((const float2*)a_s)[sp];
        for (int i = 0; i < rem; i += 4) {
            int eo = i + slot;
            bool valid = eo < rem;
            int lsrc = valid ? eo : (rem - 1);
            int s     = __shfl(sp, lsrc);
            float asx = __shfl(ap.x, lsrc);
            float asy = __shfl(ap.y, lsrc);
            const u16* hrow = hs16 + (size_t)s * HC + (cg << 3);
            uint4 g0 = *(const uint4*)hrow;          // head 0, ch cg*8..cg*8+7
            uint4 g1 = *(const uint4*)(hrow + 128);  // head 1, same channels
            float e0 = asx + ad0; e0 = (e0 >= 0.f) ? e0 : 0.2f * e0;
            float e1 = asy + ad1; e1 = (e1 >= 0.f) ? e1 : 0.2f * e1;
            float w0 = valid ? __expf(e0) : 0.f;
            float w1 = valid ? __expf(e1) : 0.f;
            w0sum += w0; w1sum += w1;
            acc0[0] += w0 * bfbits2f(g0.x & 0xFFFFu);
            acc0[1] += w0 * __uint_as_float(g0.x & 0xFFFF0000u);
            acc0[2] += w0 * bfbits2f(g0.y & 0xFFFFu);
            acc0[3] += w0 * __uint_as_float(g0.y & 0xFFFF0000u);
            acc0[4] += w0 * bfbits2f(g0.z & 0xFFFFu);
            acc0[5] += w0 * __uint_as_float(g0.z & 0xFFFF0000u);
            acc0[6] += w0 * bfbits2f(g0.w & 0xFFFFu);
            acc0[7] += w0 * __uint_as_float(g0.w & 0xFFFF0000u);
            acc1[0] += w1 * bfbits2f(g1.x & 0xFFFFu);
            acc1[1] += w1 * __uint_as_float(g1.x & 0xFFFF0000u);
            acc1[2] += w1 * bfbits2f(g1.y & 0xFFFFu);
            acc1[3] += w1 * __uint_as_float(g1.y & 0xFFFF0000u);
            acc1[4] += w1 * bfbits2f(g1.z & 0xFFFFu);
            acc1[5] += w1 * __uint_as_float(g1.z & 0xFFFF0000u);
            acc1[6] += w1 * bfbits2f(g1.w & 0xFFFFu);
            acc1[7] += w1 * __uint_as_float(g1.w & 0xFFFF0000u);
        }
    }
    // combine the 4 slots (lane bits 4 and 5)
    #pragma unroll
    for (int k = 0; k < 8; k++) {
        acc0[k] += __shfl_xor(acc0[k], 16);
        acc0[k] += __shfl_xor(acc0[k], 32);
        acc1[k] += __shfl_xor(acc1[k], 16);
        acc1[k] += __shfl_xor(acc1[k], 32);
    }
    w0sum += __shfl_xor(w0sum, 16); w0sum += __shfl_xor(w0sum, 32);
    w1sum += __shfl_xor(w1sum, 16); w1sum += __shfl_xor(w1sum, 32);
    if (lane < 16) {
        float inv0 = 1.f / (w0sum + 1e-16f), inv1 = 1.f / (w1sum + 1e-16f);
        const float4* b4 = (const float4*)bias;
        float4 bb0 = b4[cg * 2], bb1 = b4[cg * 2 + 1];
        float4 o0, o1;
        o0.x = 0.5f * (acc0[0] * inv0 + acc1[0] * inv1) + bb0.x;
        o0.y = 0.5f * (acc0[1] * inv0 + acc1[1] * inv1) + bb0.y;
        o0.z = 0.5f * (acc0[2] * inv0 + acc1[2] * inv1) + bb0.z;
        o0.w = 0.5f * (acc0[3] * inv0 + acc1[3] * inv1) + bb0.w;
        o1.x = 0.5f * (acc0[4] * inv0 + acc1[4] * inv1) + bb1.x;
        o1.y = 0.5f * (acc0[5] * inv0 + acc1[5] * inv1) + bb1.y;
        o1.z = 0.5f * (acc0[6] * inv0 + acc1[6] * inv1) + bb1.z;
        o1.w = 0.5f * (acc0[7] * inv0 + acc1[7] * inv1) + bb1.w;
        float4* op = (float4*)(out + (size_t)d * C + (cg << 3));
        op[0] = o0; op[1] = o1;
    }
}

extern "C" void kernel_launch(void* const* d_in, const int* in_sizes, int n_in,
                              void* d_out, int out_size, void* d_ws, size_t ws_size,
                              hipStream_t stream) {
    const int*   user_ids       = (const int*)d_in[0];
    const int*   ingredient_ids = (const int*)d_in[1];
    const float* recipe_x       = (const float*)d_in[2];
    const int*   ing_src        = (const int*)d_in[3];
    const int*   ing_dst        = (const int*)d_in[4];
    const int*   ub_src         = (const int*)d_in[5];
    const int*   ub_dst         = (const int*)d_in[6];
    const float* user_table     = (const float*)d_in[7];
    const float* ing_table      = (const float*)d_in[8];
    const float* W_rl           = (const float*)d_in[9];
    const float* bn_gamma       = (const float*)d_in[11];
    const float* bn_beta        = (const float*)d_in[12];
    const float* g1_ws          = (const float*)d_in[13];
    const float* g1_wd          = (const float*)d_in[14];
    const float* g1_as          = (const float*)d_in[15];
    const float* g1_ad          = (const float*)d_in[16];
    const float* g1_b           = (const float*)d_in[17];
    const float* g2_ws          = (const float*)d_in[18];
    const float* g2_wd          = (const float*)d_in[19];
    const float* g2_as          = (const float*)d_in[20];
    const float* g2_ad          = (const float*)d_in[21];
    const float* g2_b           = (const float*)d_in[22];

    int NU = in_sizes[0];
    int NI = in_sizes[1];
    int NR = in_sizes[2] / DIN;
    int E1 = in_sizes[3];
    int E2 = in_sizes[5];
    int Nmax = (NI > NU) ? NI : NU;
    int L1 = (NI < NR) ? NI : NR;
    int L2 = (NU < NR) ? NU : NR;
    int Etot = E1 + L1 + E2 + L2;
    int n2 = 2 * NR;
    int NB = (n2 + 511) >> 9;

    char* w = (char*)d_ws;
    u16*   hs16  = (u16*)w;    w += (size_t)Nmax * HC * 2;
    float* a_s   = (float*)w;  w += (size_t)Nmax * 2 * 4;
    float* psi   = (float*)w;  w += (size_t)NI * 4 * 4;
    float* a_d   = (float*)w;  w += (size_t)NR * 2 * 4;
    float* advd  = (float*)w;  w += (size_t)NR * 2 * 4;
    float* stats = (float*)w;  w += 2304 * 4;
    u16*   wsp   = (u16*)w;    w += 32768 * 2;
    u32*   bucketCnt  = (u32*)w; w += MAXNB * 4;
    u32*   bucketBase = (u32*)w; w += (MAXNB + 1) * 4;
    u32*   gcur  = (u32*)w;    w += MAXNB * 4;
    int*   off   = (int*)w;    w += (size_t)(n2 + 1) * 4;
    int*   sorted= (int*)w;    w += (size_t)Etot * 4;
    w = (char*)(((size_t)w + 15) & ~(size_t)15);
    u64*   pairs = (u64*)w;    w += (size_t)Etot * 8;

    hipMemsetAsync(stats, 0, 420 * 4, stream);
    hipMemsetAsync(bucketCnt, 0, MAXNB * 4, stream);

    // BN stats + folded constants + fused B-pack
    k_stats<<<(NR + 255) / 256, 256, 0, stream>>>(recipe_x, NR, stats);
    k_precomp_pack<<<33, 256, 0, stream>>>(stats, W_rl, bn_gamma, bn_beta,
                                           g1_wd, g1_ad, g2_wd, g2_ad,
                                           g1_ws, g1_as, g2_ws, g2_as, g1_b,
                                           1.0f / NR, wsp);
    // bucketed CSR build (both graphs, key space 2*NR)
    kA1<<<(Etot + EB1 - 1) / EB1, 256, 0, stream>>>(ing_src, ing_dst, ub_src, ub_dst,
                                                    E1, L1, E2, L2, NR, NB, bucketCnt);
    kScanB<<<1, 256, 0, stream>>>(bucketCnt, NB, n2, bucketBase, gcur, off);
    kA2<<<(Etot + EB2 - 1) / EB2, 256, 0, stream>>>(ing_src, ing_dst, ub_src, ub_dst,
                                                    E1, L1, E2, L2, NR, NB, gcur, pairs);
    kB<<<NB, 256, 0, stream>>>(pairs, bucketBase, n2, off, sorted);
    // GAT1: psi-based, no GEMM
    k_r0<<<(NR + 15) / 16, 256, 0, stream>>>(recipe_x, W_rl, stats, NR, a_d, advd);
    k_ing<<<(NI + 31) / 32, 256, 0, stream>>>(ing_table, ingredient_ids, stats, NI, a_s, psi);
    k_agg_lin<<<(NR + 3) / 4, 256, 0, stream>>>(off, sorted, a_s, psi, a_d, advd,
                                                stats + 1188, NR, a_d);
    // GAT2: MFMA hs GEMM + bf16 gather
    k_hs_mfma<<<(NU + 31) / 32, 256, 0, stream>>>(user_table, user_ids, wsp, stats, NU,
                                                  hs16, a_s);
    k_agg_gather<<<(NR + 3) / 4, 256, 0, stream>>>(off + NR, sorted, a_s, a_d, hs16,
                                                   g2_b, NR, (float*)d_out);
}

// Round 2
// 389.906 us; speedup vs baseline: 1.2277x; 1.1549x over previous
//
#include <hip/hip_runtime.h>
#include <hip/hip_bf16.h>
#include <math.h>

#define DIN 20
#define C 128
#define HC 256
#define EB1 8192
#define EB2 4096
#define MAXNB 400

typedef unsigned short u16;
typedef unsigned int u32;
typedef unsigned long long u64;
typedef __bf16 bf16x8 __attribute__((ext_vector_type(8)));
typedef float f32x4 __attribute__((ext_vector_type(4)));

__device__ __forceinline__ float bfbits2f(unsigned int lo16) {
    return __uint_as_float(lo16 << 16);
}
__device__ __forceinline__ u16 f2bf_rne(float f) {
    unsigned int b = __float_as_uint(f);
    return (u16)((b + 0x7FFFu + ((b >> 16) & 1u)) >> 16);
}

// exclusive scan of cnt[0..511] -> off[0..511] using 256 threads; tmp[256]
__device__ __forceinline__ void scan512(u32* cnt, u32* off, u32* tmp) {
    int t = threadIdx.x;
    u32 a = cnt[2 * t], b = cnt[2 * t + 1];
    u32 s = a + b;
    tmp[t] = s;
    __syncthreads();
    for (int o = 1; o < 256; o <<= 1) {
        u32 v = (t >= o) ? tmp[t - o] : 0u;
        __syncthreads();
        tmp[t] += v;
        __syncthreads();
    }
    u32 excl = tmp[t] - s;
    off[2 * t] = excl;
    off[2 * t + 1] = excl + a;
    __syncthreads();
}

// ---------------- K1: BN stats (second moment 20x20 + column sums) ----------------
__global__ __launch_bounds__(256) void k_stats(const float* __restrict__ x, int NR,
                                               float* __restrict__ stats)
{
    __shared__ float L[256][DIN];
    int t = threadIdx.x;
    int r = blockIdx.x * 256 + t;
    if (r < NR) {
        #pragma unroll
        for (int k = 0; k < DIN; k++) L[t][k] = x[r * DIN + k];
    } else {
        #pragma unroll
        for (int k = 0; k < DIN; k++) L[t][k] = 0.f;
    }
    __syncthreads();
    if (t < 210) {
        int p = 0, q = t;
        while (q >= DIN - p) { q -= (DIN - p); p++; }
        q += p;
        float acc = 0.f;
        for (int rr = 0; rr < 256; rr++) acc += L[rr][p] * L[rr][q];
        atomicAdd(&stats[p * DIN + q], acc);
        if (p != q) atomicAdd(&stats[q * DIN + p], acc);
    } else if (t < 230) {
        int k = t - 210;
        float acc = 0.f;
        for (int rr = 0; rr < 256; rr++) acc += L[rr][k];
        atomicAdd(&stats[400 + k], acc);
    }
}

// ---------------- K2: fold BN; vd1/vd2; u1/u2; T; cb; fv fold; + fused B-pack -----
// stats: [420..547]=BN scale, [548..675]=BN shift, [676..931]=vd1[c*2+h],
//        [932..1187]=vd2[c*2+h'], [1188..1189]=cb[h'],
//        [1200..1455]=u1[k*2+h], [1456..1711]=u2[k*2+h], [1712..2223]=T[k*4+h*2+h'],
//        [2240..2319]=fv[k*4+h4] (h4: 0,1=vd1 heads; 2,3=vd2 heads), [2320..2323]=cst[h4]
// block 0: precomp; blocks 1..32: pack g2_ws -> bf16 MFMA B-fragment layout
__global__ __launch_bounds__(256) void k_precomp_pack(float* __restrict__ stats,
    const float* __restrict__ W,
    const float* __restrict__ gamma, const float* __restrict__ beta,
    const float* __restrict__ g1_wd, const float* __restrict__ g1_ad,
    const float* __restrict__ g2_wd, const float* __restrict__ g2_ad,
    const float* __restrict__ g1_ws, const float* __restrict__ g1_as,
    const float* __restrict__ g2_ws, const float* __restrict__ g2_as,
    const float* __restrict__ g1b, float invN, u16* __restrict__ wsp)
{
    int t = threadIdx.x;
    if (blockIdx.x > 0) {
        // ---- pack part (former k_pack) ----
        int idx0 = ((blockIdx.x - 1) * 256 + t) * 4;
        #pragma unroll
        for (int i = 0; i < 4; i++) {
            int flat = idx0 + i;           // [nt(16)][kb(4)][lane(64)][j(8)]
            int j = flat & 7;
            int lane = (flat >> 3) & 63;
            int kb = (flat >> 9) & 3;
            int nt = flat >> 11;
            int k = kb * 32 + (lane >> 4) * 8 + j;
            int n = nt * 16 + (lane & 15);
            wsp[flat] = f2bf_rne(g2_ws[k * HC + n]);
        }
        return;
    }
    __shared__ float Sm[420];
    __shared__ float Wm[DIN * C];
    __shared__ float vd1s[256];
    __shared__ float vd2s[256];
    __shared__ float sS[128];
    __shared__ float sSh[128];
    for (int i = t; i < 420; i += 256) Sm[i] = stats[i];
    for (int i = t; i < DIN * C; i += 256) Wm[i] = W[i];
    __syncthreads();
    if (t < C) {
        float w[DIN];
        #pragma unroll
        for (int k = 0; k < DIN; k++) w[k] = Wm[k * C + t];
        float mb = 0.f;
        #pragma unroll
        for (int k = 0; k < DIN; k++) mb += Sm[400 + k] * invN * w[k];
        float e2 = 0.f;
        for (int p = 0; p < DIN; p++) {
            float acc2 = 0.f;
            #pragma unroll
            for (int q = 0; q < DIN; q++) acc2 += Sm[p * DIN + q] * w[q];
            e2 += w[p] * acc2;
        }
        e2 *= invN;
        float var = e2 - mb * mb;
        float s = gamma[t] * rsqrtf(var + 1e-5f);
        float sh = beta[t] - s * mb;   // b_rl cancels inside BN
        stats[420 + t] = s;
        stats[548 + t] = sh;
        sS[t] = s;
        sSh[t] = sh;
    }
    {
        int k = t >> 1, h = t & 1;
        const float4* wd1 = (const float4*)(g1_wd + k * HC + h * C);
        const float4* wd2 = (const float4*)(g2_wd + k * HC + h * C);
        const float4* ws1 = (const float4*)(g1_ws + k * HC + h * C);
        const float4* ws2 = (const float4*)(g2_ws + k * HC + h * C);
        const float4* ad1 = (const float4*)(g1_ad + h * C);
        const float4* ad2 = (const float4*)(g2_ad + h * C);
        const float4* as1 = (const float4*)(g1_as + h * C);
        const float4* as2 = (const float4*)(g2_as + h * C);
        float a1 = 0.f, a2 = 0.f, s1 = 0.f, s2 = 0.f;
        #pragma unroll 4
        for (int q = 0; q < 32; q++) {
            float4 x, y;
            x = wd1[q]; y = ad1[q];
            a1 += x.x * y.x + x.y * y.y + x.z * y.z + x.w * y.w;
            x = wd2[q]; y = ad2[q];
            a2 += x.x * y.x + x.y * y.y + x.z * y.z + x.w * y.w;
            x = ws1[q]; y = as1[q];
            s1 += x.x * y.x + x.y * y.y + x.z * y.z + x.w * y.w;
            x = ws2[q]; y = as2[q];
            s2 += x.x * y.x + x.y * y.y + x.z * y.z + x.w * y.w;
        }
        stats[676 + t] = a1;
        stats[932 + t] = a2;
        stats[1200 + t] = s1;
        stats[1456 + t] = s2;
        vd1s[t] = a1;
        vd2s[t] = a2;
    }
    __syncthreads();
    {
        int k = t >> 1, h = t & 1;
        const float4* ws1p = (const float4*)(g1_ws + k * HC + h * C);
        float t0 = 0.f, t1 = 0.f;
        #pragma unroll 4
        for (int q = 0; q < 32; q++) {
            float4 wv = ws1p[q];
            int c = q * 4;
            t0 += wv.x * vd2s[(c + 0) * 2 + 0] + wv.y * vd2s[(c + 1) * 2 + 0]
                + wv.z * vd2s[(c + 2) * 2 + 0] + wv.w * vd2s[(c + 3) * 2 + 0];
            t1 += wv.x * vd2s[(c + 0) * 2 + 1] + wv.y * vd2s[(c + 1) * 2 + 1]
                + wv.z * vd2s[(c + 2) * 2 + 1] + wv.w * vd2s[(c + 3) * 2 + 1];
        }
        stats[1712 + t * 2 + 0] = t0;
        stats[1712 + t * 2 + 1] = t1;
    }
    if (t < 2) {
        float cb = 0.f;
        for (int k = 0; k < C; k++) cb += g1b[k] * vd2s[k * 2 + t];
        stats[1188 + t] = cb;
    }
    // folded r0 vectors: fv[k][h4] = sum_c s[c]*W[k][c]*vd{1,2}[c][h]
    if (t < 80) {
        int k = t >> 2, h4 = t & 3, h = h4 & 1;
        const float* vs = (h4 < 2) ? vd1s : vd2s;
        float acc = 0.f;
        for (int c = 0; c < C; c++) acc += sS[c] * Wm[k * C + c] * vs[c * 2 + h];
        stats[2240 + t] = acc;
    } else if (t < 84) {
        int h4 = t - 80, h = h4 & 1;
        const float* vs = (h4 < 2) ? vd1s : vd2s;
        float acc = 0.f;
        for (int c = 0; c < C; c++) acc += sSh[c] * vs[c * 2 + h];
        stats[2320 + h4] = acc;
    }
}

// ---------------- K3 (folded): a_d/advd = x @ fv + cst  ([NR,20]x[20,4] GEMV) -----
__global__ __launch_bounds__(256) void k_r0f(const float* __restrict__ x,
    const float* __restrict__ stats, int NR,
    float* __restrict__ a_d, float* __restrict__ advd)
{
    __shared__ float xr[256 * 21];   // +1 pad: stride 21 coprime w/ 32 banks
    __shared__ float fv[84];
    int t = threadIdx.x;
    if (t < 84) fv[t] = stats[2240 + t];
    int r0 = blockIdx.x * 256;
    int nRows = NR - r0; if (nRows > 256) nRows = 256;
    int total = nRows * DIN;
    const float* xb = x + (size_t)r0 * DIN;
    for (int i = t; i < total; i += 256) {
        int row = i / DIN;
        int col = i - row * DIN;
        xr[row * 21 + col] = xb[i];
    }
    __syncthreads();
    if (t < nRows) {
        const float* xp = &xr[t * 21];
        float a0 = 0.f, a1 = 0.f, b0 = 0.f, b1 = 0.f;
        #pragma unroll
        for (int k = 0; k < DIN; k++) {
            float xv = xp[k];
            a0 += xv * fv[k * 4 + 0];
            a1 += xv * fv[k * 4 + 1];
            b0 += xv * fv[k * 4 + 2];
            b1 += xv * fv[k * 4 + 3];
        }
        int r = r0 + t;
        ((float2*)a_d)[r]  = make_float2(a0 + fv[80], a1 + fv[81]);
        ((float2*)advd)[r] = make_float2(b0 + fv[82], b1 + fv[83]);
    }
}

// ---------------- K_ing: ingredient path = pure gather + 6 dots per row -----------
__global__ __launch_bounds__(256) void k_ing(const float* __restrict__ table,
    const int* __restrict__ ids, const float* __restrict__ stats,
    int Ns, float* __restrict__ a_s, float* __restrict__ psi)
{
    __shared__ float u1s[256];
    __shared__ float Ts[512];
    int t = threadIdx.x;
    u1s[t] = stats[1200 + t];
    Ts[t] = stats[1712 + t];
    Ts[256 + t] = stats[1968 + t];
    __syncthreads();
    int r = t >> 3, cg = t & 7;
    int row = blockIdx.x * 32 + r;
    float as0 = 0.f, as1 = 0.f, p00 = 0.f, p01 = 0.f, p10 = 0.f, p11 = 0.f;
    if (row < Ns) {
        const float* xp = table + (size_t)ids[row] * C + cg * 16;
        #pragma unroll
        for (int q = 0; q < 4; q++) {
            float4 v = ((const float4*)xp)[q];
            float xv[4] = {v.x, v.y, v.z, v.w};
            #pragma unroll
            for (int jj = 0; jj < 4; jj++) {
                int k = cg * 16 + q * 4 + jj;
                float xx = xv[jj];
                as0 += xx * u1s[k * 2 + 0];
                as1 += xx * u1s[k * 2 + 1];
                p00 += xx * Ts[k * 4 + 0];
                p01 += xx * Ts[k * 4 + 1];
                p10 += xx * Ts[k * 4 + 2];
                p11 += xx * Ts[k * 4 + 3];
            }
        }
    }
    #pragma unroll
    for (int m = 1; m <= 4; m <<= 1) {
        as0 += __shfl_xor(as0, m); as1 += __shfl_xor(as1, m);
        p00 += __shfl_xor(p00, m); p01 += __shfl_xor(p01, m);
        p10 += __shfl_xor(p10, m); p11 += __shfl_xor(p11, m);
    }
    if (cg == 0 && row < Ns) {
        ((float2*)a_s)[row] = make_float2(as0, as1);
        float4 pv; pv.x = p00; pv.y = p01; pv.z = p10; pv.w = p11;
        ((float4*)psi)[row] = pv;
    }
}

// ---------------- K_hs_mfma: user hs GEMM via MFMA + a_s via u2 -------------------
__global__ __launch_bounds__(256) void k_hs_mfma(const float* __restrict__ table,
    const int* __restrict__ ids, const u16* __restrict__ wsp,
    const float* __restrict__ stats, int Ns,
    u16* __restrict__ hs16, float* __restrict__ a_s)
{
    __shared__ __align__(16) u16 A[32 * 136];
    __shared__ float u2s[256];
    int t = threadIdx.x;
    u2s[t] = stats[1456 + t];
    int rowBase = blockIdx.x * 32;
    int r = t >> 3, cg = t & 7;
    int row = rowBase + r;
    float xv[16];
    if (row < Ns) {
        const float* xp = table + (size_t)ids[row] * C + cg * 16;
        #pragma unroll
        for (int q = 0; q < 4; q++) {
            float4 v = ((const float4*)xp)[q];
            xv[q * 4 + 0] = v.x; xv[q * 4 + 1] = v.y;
            xv[q * 4 + 2] = v.z; xv[q * 4 + 3] = v.w;
        }
    } else {
        #pragma unroll
        for (int q = 0; q < 16; q++) xv[q] = 0.f;
    }
    float ss = 0.f;
    #pragma unroll
    for (int q = 0; q < 16; q++) ss += xv[q] * xv[q];
    #pragma unroll
    for (int m = 1; m <= 4; m <<= 1) ss += __shfl_xor(ss, m);
    float nn = sqrtf(ss);
    float f = (nn > 1.f) ? 1.f / (nn + 1e-7f) : 1.f;
    float as0 = 0.f, as1 = 0.f;
    #pragma unroll
    for (int q = 0; q < 16; q++) {
        xv[q] *= f;
        int k = cg * 16 + q;
        as0 += xv[q] * u2s[k * 2 + 0];
        as1 += xv[q] * u2s[k * 2 + 1];
    }
    #pragma unroll
    for (int m = 1; m <= 4; m <<= 1) {
        as0 += __shfl_xor(as0, m); as1 += __shfl_xor(as1, m);
    }
    if (cg == 0 && row < Ns) ((float2*)a_s)[row] = make_float2(as0, as1);
    {
        union { u16 h[16]; uint4 u4[2]; } pk;
        #pragma unroll
        for (int q = 0; q < 16; q++) pk.h[q] = f2bf_rne(xv[q]);
        uint4* dst = (uint4*)&A[r * 136 + cg * 16];
        dst[0] = pk.u4[0];
        dst[1] = pk.u4[1];
    }
    __syncthreads();
    int w = t >> 6, l = t & 63;
    int m15 = l & 15, q4 = l >> 4;
    bf16x8 afrag[2][4];
    #pragma unroll
    for (int mt = 0; mt < 2; mt++)
        #pragma unroll
        for (int kb = 0; kb < 4; kb++)
            afrag[mt][kb] = *(const bf16x8*)&A[(mt * 16 + m15) * 136 + kb * 32 + q4 * 8];
    f32x4 acc[2][4];
    #pragma unroll
    for (int mt = 0; mt < 2; mt++)
        #pragma unroll
        for (int i = 0; i < 4; i++) acc[mt][i] = (f32x4){0.f, 0.f, 0.f, 0.f};
    #pragma unroll
    for (int kb = 0; kb < 4; kb++) {
        #pragma unroll
        for (int i = 0; i < 4; i++) {
            int nt = w * 4 + i;
            bf16x8 bfrag = *(const bf16x8*)&wsp[((nt * 4 + kb) * 64 + l) * 8];
            acc[0][i] = __builtin_amdgcn_mfma_f32_16x16x32_bf16(afrag[0][kb], bfrag, acc[0][i], 0, 0, 0);
            acc[1][i] = __builtin_amdgcn_mfma_f32_16x16x32_bf16(afrag[1][kb], bfrag, acc[1][i], 0, 0, 0);
        }
    }
    #pragma unroll
    for (int mt = 0; mt < 2; mt++) {
        #pragma unroll
        for (int i = 0; i < 4; i++) {
            int col = (w * 4 + i) * 16 + m15;
            #pragma unroll
            for (int rr = 0; rr < 4; rr++) {
                int rw = rowBase + mt * 16 + q4 * 4 + rr;
                if (rw < Ns) hs16[(size_t)rw * HC + col] = f2bf_rne(acc[mt][i][rr]);
            }
        }
    }
}

// ================= Bucketed CSR build =================
// key space [0, 2*NR): graph1 key=d, graph2 key=NR+d. bucket = key>>9.

__device__ __forceinline__ void edge_at(int i, const int* s1, const int* d1,
    const int* s2, const int* d2, int E1, int T1, int E2, int NR,
    int& s, int& key)
{
    if (i < T1) {
        if (i < E1) { s = s1[i]; key = d1[i]; }
        else        { s = i - E1; key = i - E1; }
    } else {
        int k = i - T1;
        if (k < E2) { s = s2[k]; key = NR + d2[k]; }
        else        { s = k - E2; key = NR + (k - E2); }
    }
}

// A1: per-block LDS bucket histogram -> global bucketCnt
__global__ __launch_bounds__(256) void kA1(const int* __restrict__ src1, const int* __restrict__ dst1,
    const int* __restrict__ src2, const int* __restrict__ dst2,
    int E1, int L1, int E2, int L2, int NR, int NB, u32* __restrict__ bucketCnt)
{
    __shared__ u32 cnt[MAXNB];
    int t = threadIdx.x;
    for (int i = t; i < NB; i += 256) cnt[i] = 0;
    __syncthreads();
    int T1 = E1 + L1, T = T1 + E2 + L2;
    int base = blockIdx.x * EB1;
    int nE = T - base; if (nE > EB1) nE = EB1;
    for (int j = t; j < nE; j += 256) {
        int s, key;
        edge_at(base + j, src1, dst1, src2, dst2, E1, T1, E2, NR, s, key);
        atomicAdd(&cnt[key >> 9], 1u);
    }
    __syncthreads();
    for (int b = t; b < NB; b += 256) {
        u32 c = cnt[b];
        if (c) atomicAdd(&bucketCnt[b], c);
    }
}

// scanB: PARALLEL scan over NB buckets -> bucketBase, gcur; off[n2] = Etot
__global__ __launch_bounds__(256) void kScanB(const u32* __restrict__ bucketCnt, int NB, int n2,
                       u32* __restrict__ bucketBase, u32* __restrict__ gcur,
                       int* __restrict__ off)
{
    __shared__ u32 cnt[512], offL[512], tmp[256];
    int t = threadIdx.x;
    for (int i = t; i < 512; i += 256) cnt[i] = (i < NB) ? bucketCnt[i] : 0u;
    __syncthreads();
    scan512(cnt, offL, tmp);
    for (int i = t; i < NB; i += 256) {
        u32 v = offL[i];
        bucketBase[i] = v;
        gcur[i] = v;
    }
    if (t == 0) {
        u32 total = offL[511] + cnt[511];
        bucketBase[NB] = total;
        off[n2] = (int)total;
    }
}

// A2: local counting sort by bucket, contiguous run writes of packed (key,src)
__global__ __launch_bounds__(256) void kA2(const int* __restrict__ src1, const int* __restrict__ dst1,
    const int* __restrict__ src2, const int* __restrict__ dst2,
    int E1, int L1, int E2, int L2, int NR, int NB,
    u32* __restrict__ gcur, u64* __restrict__ pairs)
{
    __shared__ u64 ldsE[EB2];
    __shared__ u64 ldsS[EB2];
    __shared__ u32 cntA[512], cntB[512], offL[512], tmp[256];
    __shared__ u32 gbase[MAXNB];
    int t = threadIdx.x;
    for (int i = t; i < 512; i += 256) { cntA[i] = 0; cntB[i] = 0; }
    __syncthreads();
    int T1 = E1 + L1, T = T1 + E2 + L2;
    int base = blockIdx.x * EB2;
    int nE = T - base; if (nE > EB2) nE = EB2;
    for (int j = t; j < nE; j += 256) {
        int s, key;
        edge_at(base + j, src1, dst1, src2, dst2, E1, T1, E2, NR, s, key);
        ldsE[j] = ((u64)(u32)key << 32) | (u32)s;
        atomicAdd(&cntA[key >> 9], 1u);
    }
    __syncthreads();
    scan512(cntA, offL, tmp);
    for (int b = t; b < NB; b += 256) {
        u32 c = cntA[b];
        gbase[b] = c ? atomicAdd(&gcur[b], c) : 0u;
    }
    __syncthreads();
    for (int j = t; j < nE; j += 256) {
        u64 e = ldsE[j];
        u32 b = ((u32)(e >> 32)) >> 9;
        u32 r = atomicAdd(&cntB[b], 1u);
        ldsS[offL[b] + r] = e;
    }
    __syncthreads();
    for (int j = t; j < nE; j += 256) {
        u64 e = ldsS[j];
        u32 b = ((u32)(e >> 32)) >> 9;
        pairs[gbase[b] + ((u32)j - offL[b])] = e;
    }
}

// B: per-bucket fine sort -> off[] + sorted[] (sequential writes)
__global__ __launch_bounds__(256) void kB(const u64* __restrict__ pairs,
    const u32* __restrict__ bucketBase, int n2,
    int* __restrict__ off, int* __restrict__ sorted)
{
    __shared__ u32 cntA[512], cntB[512], offL[512], tmp[256];
    __shared__ u32 ldsS[8192];
    int b = blockIdx.x;
    int t = threadIdx.x;
    u32 beg = bucketBase[b], end = bucketBase[b + 1];
    int dstBase = b << 9;
    for (int i = t; i < 512; i += 256) { cntA[i] = 0; cntB[i] = 0; }
    __syncthreads();
    for (u32 j = beg + t; j < end; j += 256) {
        u32 key = (u32)(pairs[j] >> 32);
        atomicAdd(&cntA[key - dstBase], 1u);
    }
    __syncthreads();
    scan512(cntA, offL, tmp);
    for (int d = t; d < 512; d += 256) {
        int gk = dstBase + d;
        if (gk < n2) off[gk] = (int)(beg + offL[d]);
    }
    u32 cnt = end - beg;
    bool fast = cnt <= 8192u;
    __syncthreads();
    for (u32 j = beg + t; j < end; j += 256) {
        u64 e = pairs[j];
        u32 d = (u32)(e >> 32) - dstBase;
        u32 r = atomicAdd(&cntB[d], 1u);
        u32 pos = offL[d] + r;
        if (fast) ldsS[pos] = (u32)e;
        else sorted[beg + pos] = (int)(u32)e;
    }
    __syncthreads();
    if (fast) {
        for (u32 j = t; j < cnt; j += 256) sorted[beg + j] = (int)ldsS[j];
    }
}

// ---------------- GAT1 agg: 16B-per-edge psi aggregation (wave per dst) -----------
__global__ __launch_bounds__(256) void k_agg_lin(const int* __restrict__ off, const int* __restrict__ sorted,
    const float* __restrict__ a_s, const float* __restrict__ psi,
    const float* __restrict__ a_d, const float* __restrict__ advd,
    const float* __restrict__ cb, int NR, float* __restrict__ a_d_out)
{
    int wave = threadIdx.x >> 6, lane = threadIdx.x & 63;
    int d = blockIdx.x * 4 + wave;
    if (d >= NR) return;
    int beg = off[d], end = off[d + 1];
    float ad0 = a_d[d * 2 + 0], ad1 = a_d[d * 2 + 1];
    float w0s = 0.f, w1s = 0.f, a00 = 0.f, a01 = 0.f, a10 = 0.f, a11 = 0.f;
    for (int j = beg + lane; j < end; j += 64) {
        int s = sorted[j];
        float2 as = ((const float2*)a_s)[s];
        float e0 = as.x + ad0; e0 = (e0 >= 0.f) ? e0 : 0.2f * e0;
        float e1 = as.y + ad1; e1 = (e1 >= 0.f) ? e1 : 0.2f * e1;
        float x0 = __expf(e0), x1 = __expf(e1);
        float4 p = ((const float4*)psi)[s];
        w0s += x0; w1s += x1;
        a00 += x0 * p.x; a01 += x0 * p.y;
        a10 += x1 * p.z; a11 += x1 * p.w;
    }
    #pragma unroll
    for (int o = 32; o; o >>= 1) {
        w0s += __shfl_down(w0s, o); w1s += __shfl_down(w1s, o);
        a00 += __shfl_down(a00, o); a01 += __shfl_down(a01, o);
        a10 += __shfl_down(a10, o); a11 += __shfl_down(a11, o);
    }
    if (lane == 0) {
        float inv0 = 1.f / (w0s + 1e-16f), inv1 = 1.f / (w1s + 1e-16f);
        a_d_out[d * 2 + 0] = advd[d * 2 + 0] + cb[0] + 0.5f * (a00 * inv0 + a10 * inv1);
        a_d_out[d * 2 + 1] = advd[d * 2 + 1] + cb[1] + 0.5f * (a01 * inv0 + a11 * inv1);
    }
}

// ---------------- GAT2 agg: fused single-pass bf16 gather (wave per dst) ----------
// 4 edges in flight per wave (16 lanes/edge); each lane loads BOTH head slices
// (2 x 16B) and keeps per-head accumulators.
__global__ __launch_bounds__(256) void k_agg_gather(const int* __restrict__ off, const int* __restrict__ sorted,
    const float* __restrict__ a_s, const float* __restrict__ a_d,
    const u16* __restrict__ hs16, const float* __restrict__ bias,
    int NR, float* __restrict__ out)
{
    int wave = threadIdx.x >> 6, lane = threadIdx.x & 63;
    int d = blockIdx.x * 4 + wave;
    if (d >= NR) return;
    int beg = off[d], end = off[d + 1];
    int slot = lane >> 4;      // which of 4 concurrent edges
    int cg = lane & 15;        // channel group: 8 channels per head
    float ad0 = a_d[d * 2 + 0], ad1 = a_d[d * 2 + 1];
    float w0sum = 0.f, w1sum = 0.f;
    float acc0[8], acc1[8];
    #pragma unroll
    for (int k = 0; k < 8; k++) { acc0[k] = 0.f; acc1[k] = 0.f; }

    for (int base = beg; base < end; base += 64) {
        int rem = end - base; if (rem > 64) rem = 64;
        int pidx = base + ((lane < rem) ? lane : (rem - 1));
        int sp = sorted[pidx];
        float2 ap = ((const float2*)a_s)[sp];
        for (int i = 0; i < rem; i += 4) {
            int eo = i + slot;
            bool valid = eo < rem;
            int lsrc = valid ? eo : (rem - 1);
            int s     = __shfl(sp, lsrc);
            float asx = __shfl(ap.x, lsrc);
            float asy = __shfl(ap.y, lsrc);
            const u16* hrow = hs16 + (size_t)s * HC + (cg << 3);
            uint4 g0 = *(const uint4*)hrow;          // head 0, ch cg*8..cg*8+7
            uint4 g1 = *(const uint4*)(hrow + 128);  // head 1, same channels
            float e0 = asx + ad0; e0 = (e0 >= 0.f) ? e0 : 0.2f * e0;
            float e1 = asy + ad1; e1 = (e1 >= 0.f) ? e1 : 0.2f * e1;
            float w0 = valid ? __expf(e0) : 0.f;
            float w1 = valid ? __expf(e1) : 0.f;
            w0sum += w0; w1sum += w1;
            acc0[0] += w0 * bfbits2f(g0.x & 0xFFFFu);
            acc0[1] += w0 * __uint_as_float(g0.x & 0xFFFF0000u);
            acc0[2] += w0 * bfbits2f(g0.y & 0xFFFFu);
            acc0[3] += w0 * __uint_as_float(g0.y & 0xFFFF0000u);
            acc0[4] += w0 * bfbits2f(g0.z & 0xFFFFu);
            acc0[5] += w0 * __uint_as_float(g0.z & 0xFFFF0000u);
            acc0[6] += w0 * bfbits2f(g0.w & 0xFFFFu);
            acc0[7] += w0 * __uint_as_float(g0.w & 0xFFFF0000u);
            acc1[0] += w1 * bfbits2f(g1.x & 0xFFFFu);
            acc1[1] += w1 * __uint_as_float(g1.x & 0xFFFF0000u);
            acc1[2] += w1 * bfbits2f(g1.y & 0xFFFFu);
            acc1[3] += w1 * __uint_as_float(g1.y & 0xFFFF0000u);
            acc1[4] += w1 * bfbits2f(g1.z & 0xFFFFu);
            acc1[5] += w1 * __uint_as_float(g1.z & 0xFFFF0000u);
            acc1[6] += w1 * bfbits2f(g1.w & 0xFFFFu);
            acc1[7] += w1 * __uint_as_float(g1.w & 0xFFFF0000u);
        }
    }
    // combine the 4 slots (lane bits 4 and 5)
    #pragma unroll
    for (int k = 0; k < 8; k++) {
        acc0[k] += __shfl_xor(acc0[k], 16);
        acc0[k] += __shfl_xor(acc0[k], 32);
        acc1[k] += __shfl_xor(acc1[k], 16);
        acc1[k] += __shfl_xor(acc1[k], 32);
    }
    w0sum += __shfl_xor(w0sum, 16); w0sum += __shfl_xor(w0sum, 32);
    w1sum += __shfl_xor(w1sum, 16); w1sum += __shfl_xor(w1sum, 32);
    if (lane < 16) {
        float inv0 = 1.f / (w0sum + 1e-16f), inv1 = 1.f / (w1sum + 1e-16f);
        const float4* b4 = (const float4*)bias;
        float4 bb0 = b4[cg * 2], bb1 = b4[cg * 2 + 1];
        float4 o0, o1;
        o0.x = 0.5f * (acc0[0] * inv0 + acc1[0] * inv1) + bb0.x;
        o0.y = 0.5f * (acc0[1] * inv0 + acc1[1] * inv1) + bb0.y;
        o0.z = 0.5f * (acc0[2] * inv0 + acc1[2] * inv1) + bb0.z;
        o0.w = 0.5f * (acc0[3] * inv0 + acc1[3] * inv1) + bb0.w;
        o1.x = 0.5f * (acc0[4] * inv0 + acc1[4] * inv1) + bb1.x;
        o1.y = 0.5f * (acc0[5] * inv0 + acc1[5] * inv1) + bb1.y;
        o1.z = 0.5f * (acc0[6] * inv0 + acc1[6] * inv1) + bb1.z;
        o1.w = 0.5f * (acc0[7] * inv0 + acc1[7] * inv1) + bb1.w;
        float4* op = (float4*)(out + (size_t)d * C + (cg << 3));
        op[0] = o0; op[1] = o1;
    }
}

extern "C" void kernel_launch(void* const* d_in, const int* in_sizes, int n_in,
                              void* d_out, int out_size, void* d_ws, size_t ws_size,
                              hipStream_t stream) {
    const int*   user_ids       = (const int*)d_in[0];
    const int*   ingredient_ids = (const int*)d_in[1];
    const float* recipe_x       = (const float*)d_in[2];
    const int*   ing_src        = (const int*)d_in[3];
    const int*   ing_dst        = (const int*)d_in[4];
    const int*   ub_src         = (const int*)d_in[5];
    const int*   ub_dst         = (const int*)d_in[6];
    const float* user_table     = (const float*)d_in[7];
    const float* ing_table      = (const float*)d_in[8];
    const float* W_rl           = (const float*)d_in[9];
    const float* bn_gamma       = (const float*)d_in[11];
    const float* bn_beta        = (const float*)d_in[12];
    const float* g1_ws          = (const float*)d_in[13];
    const float* g1_wd          = (const float*)d_in[14];
    const float* g1_as          = (const float*)d_in[15];
    const float* g1_ad          = (const float*)d_in[16];
    const float* g1_b           = (const float*)d_in[17];
    const float* g2_ws          = (const float*)d_in[18];
    const float* g2_wd          = (const float*)d_in[19];
    const float* g2_as          = (const float*)d_in[20];
    const float* g2_ad          = (const float*)d_in[21];
    const float* g2_b           = (const float*)d_in[22];

    int NU = in_sizes[0];
    int NI = in_sizes[1];
    int NR = in_sizes[2] / DIN;
    int E1 = in_sizes[3];
    int E2 = in_sizes[5];
    int Nmax = (NI > NU) ? NI : NU;
    int L1 = (NI < NR) ? NI : NR;
    int L2 = (NU < NR) ? NU : NR;
    int Etot = E1 + L1 + E2 + L2;
    int n2 = 2 * NR;
    int NB = (n2 + 511) >> 9;

    char* w = (char*)d_ws;
    u16*   hs16  = (u16*)w;    w += (size_t)Nmax * HC * 2;
    float* a_s   = (float*)w;  w += (size_t)Nmax * 2 * 4;
    float* psi   = (float*)w;  w += (size_t)NI * 4 * 4;
    float* a_d   = (float*)w;  w += (size_t)NR * 2 * 4;
    float* advd  = (float*)w;  w += (size_t)NR * 2 * 4;
    float* stats = (float*)w;  w += 2432 * 4;
    u16*   wsp   = (u16*)w;    w += 32768 * 2;
    u32*   bucketCnt  = (u32*)w; w += MAXNB * 4;
    u32*   bucketBase = (u32*)w; w += (MAXNB + 1) * 4;
    u32*   gcur  = (u32*)w;    w += MAXNB * 4;
    int*   off   = (int*)w;    w += (size_t)(n2 + 1) * 4;
    int*   sorted= (int*)w;    w += (size_t)Etot * 4;
    w = (char*)(((size_t)w + 15) & ~(size_t)15);
    u64*   pairs = (u64*)w;    w += (size_t)Etot * 8;

    hipMemsetAsync(stats, 0, 420 * 4, stream);
    hipMemsetAsync(bucketCnt, 0, MAXNB * 4, stream);

    // BN stats + folded constants + fused B-pack
    k_stats<<<(NR + 255) / 256, 256, 0, stream>>>(recipe_x, NR, stats);
    k_precomp_pack<<<33, 256, 0, stream>>>(stats, W_rl, bn_gamma, bn_beta,
                                           g1_wd, g1_ad, g2_wd, g2_ad,
                                           g1_ws, g1_as, g2_ws, g2_as, g1_b,
                                           1.0f / NR, wsp);
    // bucketed CSR build (both graphs, key space 2*NR)
    kA1<<<(Etot + EB1 - 1) / EB1, 256, 0, stream>>>(ing_src, ing_dst, ub_src, ub_dst,
                                                    E1, L1, E2, L2, NR, NB, bucketCnt);
    kScanB<<<1, 256, 0, stream>>>(bucketCnt, NB, n2, bucketBase, gcur, off);
    kA2<<<(Etot + EB2 - 1) / EB2, 256, 0, stream>>>(ing_src, ing_dst, ub_src, ub_dst,
                                                    E1, L1, E2, L2, NR, NB, gcur, pairs);
    kB<<<NB, 256, 0, stream>>>(pairs, bucketBase, n2, off, sorted);
    // GAT1: psi-based, no GEMM (a_d/advd via folded GEMV)
    k_r0f<<<(NR + 255) / 256, 256, 0, stream>>>(recipe_x, stats, NR, a_d, advd);
    k_ing<<<(NI + 31) / 32, 256, 0, stream>>>(ing_table, ingredient_ids, stats, NI, a_s, psi);
    k_agg_lin<<<(NR + 3) / 4, 256, 0, stream>>>(off, sorted, a_s, psi, a_d, advd,
                                                stats + 1188, NR, a_d);
    // GAT2: MFMA hs GEMM + bf16 gather
    k_hs_mfma<<<(NU + 31) / 32, 256, 0, stream>>>(user_table, user_ids, wsp, stats, NU,
                                                  hs16, a_s);
    k_agg_gather<<<(NR + 3) / 4, 256, 0, stream>>>(off + NR, sorted, a_s, a_d, hs16,
                                                   g2_b, NR, (float*)d_out);
}

// Round 3
// 377.390 us; speedup vs baseline: 1.2684x; 1.0332x over previous
//
#include <hip/hip_runtime.h>
#include <hip/hip_bf16.h>
#include <math.h>

#define DIN 20
#define C 128
#define HC 256
#define EB1 8192
#define EB2 4096
#define MAXNB 400

typedef unsigned short u16;
typedef unsigned int u32;
typedef unsigned long long u64;
typedef __bf16 bf16x8 __attribute__((ext_vector_type(8)));
typedef float f32x4 __attribute__((ext_vector_type(4)));

__device__ __forceinline__ float bfbits2f(unsigned int lo16) {
    return __uint_as_float(lo16 << 16);
}
__device__ __forceinline__ u16 f2bf_rne(float f) {
    unsigned int b = __float_as_uint(f);
    return (u16)((b + 0x7FFFu + ((b >> 16) & 1u)) >> 16);
}

// exclusive scan of cnt[0..511] -> off[0..511] using 256 threads; tmp[256]
__device__ __forceinline__ void scan512(u32* cnt, u32* off, u32* tmp) {
    int t = threadIdx.x;
    u32 a = cnt[2 * t], b = cnt[2 * t + 1];
    u32 s = a + b;
    tmp[t] = s;
    __syncthreads();
    for (int o = 1; o < 256; o <<= 1) {
        u32 v = (t >= o) ? tmp[t - o] : 0u;
        __syncthreads();
        tmp[t] += v;
        __syncthreads();
    }
    u32 excl = tmp[t] - s;
    off[2 * t] = excl;
    off[2 * t + 1] = excl + a;
    __syncthreads();
}

__device__ __forceinline__ void edge_at(int i, const int* s1, const int* d1,
    const int* s2, const int* d2, int E1, int T1, int E2, int NR,
    int& s, int& key)
{
    if (i < T1) {
        if (i < E1) { s = s1[i]; key = d1[i]; }
        else        { s = i - E1; key = i - E1; }
    } else {
        int k = i - T1;
        if (k < E2) { s = s2[k]; key = NR + d2[k]; }
        else        { s = k - E2; key = NR + (k - E2); }
    }
}

// ---------------- K_init: fused BN stats + kA1 bucket histogram -------------------
// blocks [0, SB): BN stats; blocks [SB, SB+AB): edge bucket histogram
__global__ __launch_bounds__(256) void k_init(const float* __restrict__ x, int NR,
    float* __restrict__ stats, int SB,
    const int* __restrict__ src1, const int* __restrict__ dst1,
    const int* __restrict__ src2, const int* __restrict__ dst2,
    int E1, int L1, int E2, int L2, int NB, u32* __restrict__ bucketCnt)
{
    __shared__ float L[256][DIN];
    __shared__ u32 cnt[MAXNB];
    int t = threadIdx.x;
    if (blockIdx.x < SB) {
        int r = blockIdx.x * 256 + t;
        if (r < NR) {
            #pragma unroll
            for (int k = 0; k < DIN; k++) L[t][k] = x[r * DIN + k];
        } else {
            #pragma unroll
            for (int k = 0; k < DIN; k++) L[t][k] = 0.f;
        }
        __syncthreads();
        if (t < 210) {
            int p = 0, q = t;
            while (q >= DIN - p) { q -= (DIN - p); p++; }
            q += p;
            float acc = 0.f;
            for (int rr = 0; rr < 256; rr++) acc += L[rr][p] * L[rr][q];
            atomicAdd(&stats[p * DIN + q], acc);
            if (p != q) atomicAdd(&stats[q * DIN + p], acc);
        } else if (t < 230) {
            int k = t - 210;
            float acc = 0.f;
            for (int rr = 0; rr < 256; rr++) acc += L[rr][k];
            atomicAdd(&stats[400 + k], acc);
        }
        return;
    }
    // ---- kA1 role ----
    for (int i = t; i < NB; i += 256) cnt[i] = 0;
    __syncthreads();
    int T1 = E1 + L1, T = T1 + E2 + L2;
    int base = (blockIdx.x - SB) * EB1;
    int nE = T - base; if (nE > EB1) nE = EB1;
    for (int j = t; j < nE; j += 256) {
        int s, key;
        edge_at(base + j, src1, dst1, src2, dst2, E1, T1, E2, NR, s, key);
        atomicAdd(&cnt[key >> 9], 1u);
    }
    __syncthreads();
    for (int b = t; b < NB; b += 256) {
        u32 c = cnt[b];
        if (c) atomicAdd(&bucketCnt[b], c);
    }
}

// ---------------- K2: precomp (block 0) + B-pack (1..32) + bucket scan (33) -------
// stats: [420..547]=BN scale, [548..675]=BN shift, [676..931]=vd1[c*2+h],
//        [932..1187]=vd2[c*2+h'], [1188..1189]=cb[h'],
//        [1200..1455]=u1[k*2+h], [1456..1711]=u2[k*2+h], [1712..2223]=T[k*4+h*2+h'],
//        [2240..2319]=fv[k*4+h4], [2320..2323]=cst[h4]
__global__ __launch_bounds__(256) void k_precomp_pack(float* __restrict__ stats,
    const float* __restrict__ W,
    const float* __restrict__ gamma, const float* __restrict__ beta,
    const float* __restrict__ g1_wd, const float* __restrict__ g1_ad,
    const float* __restrict__ g2_wd, const float* __restrict__ g2_ad,
    const float* __restrict__ g1_ws, const float* __restrict__ g1_as,
    const float* __restrict__ g2_ws, const float* __restrict__ g2_as,
    const float* __restrict__ g1b, float invN, u16* __restrict__ wsp,
    const u32* __restrict__ bucketCnt, int NB, int n2,
    u32* __restrict__ bucketBase, u32* __restrict__ gcur, int* __restrict__ off)
{
    int t = threadIdx.x;
    if (blockIdx.x == 33) {
        // ---- bucket scan role (former kScanB) ----
        __shared__ u32 cnt[512], offL[512], tmp[256];
        for (int i = t; i < 512; i += 256) cnt[i] = (i < NB) ? bucketCnt[i] : 0u;
        __syncthreads();
        scan512(cnt, offL, tmp);
        for (int i = t; i < NB; i += 256) {
            u32 v = offL[i];
            bucketBase[i] = v;
            gcur[i] = v;
        }
        if (t == 0) {
            u32 total = offL[511] + cnt[511];
            bucketBase[NB] = total;
            off[n2] = (int)total;
        }
        return;
    }
    if (blockIdx.x > 0) {
        // ---- pack role ----
        int idx0 = ((blockIdx.x - 1) * 256 + t) * 4;
        #pragma unroll
        for (int i = 0; i < 4; i++) {
            int flat = idx0 + i;           // [nt(16)][kb(4)][lane(64)][j(8)]
            int j = flat & 7;
            int lane = (flat >> 3) & 63;
            int kb = (flat >> 9) & 3;
            int nt = flat >> 11;
            int k = kb * 32 + (lane >> 4) * 8 + j;
            int n = nt * 16 + (lane & 15);
            wsp[flat] = f2bf_rne(g2_ws[k * HC + n]);
        }
        return;
    }
    __shared__ float Sm[420];
    __shared__ float Wm[DIN * C];
    __shared__ float vd1s[256];
    __shared__ float vd2s[256];
    __shared__ float sS[128];
    __shared__ float sSh[128];
    for (int i = t; i < 420; i += 256) Sm[i] = stats[i];
    for (int i = t; i < DIN * C; i += 256) Wm[i] = W[i];
    __syncthreads();
    if (t < C) {
        float w[DIN];
        #pragma unroll
        for (int k = 0; k < DIN; k++) w[k] = Wm[k * C + t];
        float mb = 0.f;
        #pragma unroll
        for (int k = 0; k < DIN; k++) mb += Sm[400 + k] * invN * w[k];
        float e2 = 0.f;
        for (int p = 0; p < DIN; p++) {
            float acc2 = 0.f;
            #pragma unroll
            for (int q = 0; q < DIN; q++) acc2 += Sm[p * DIN + q] * w[q];
            e2 += w[p] * acc2;
        }
        e2 *= invN;
        float var = e2 - mb * mb;
        float s = gamma[t] * rsqrtf(var + 1e-5f);
        float sh = beta[t] - s * mb;   // b_rl cancels inside BN
        stats[420 + t] = s;
        stats[548 + t] = sh;
        sS[t] = s;
        sSh[t] = sh;
    }
    {
        int k = t >> 1, h = t & 1;
        const float4* wd1 = (const float4*)(g1_wd + k * HC + h * C);
        const float4* wd2 = (const float4*)(g2_wd + k * HC + h * C);
        const float4* ws1 = (const float4*)(g1_ws + k * HC + h * C);
        const float4* ws2 = (const float4*)(g2_ws + k * HC + h * C);
        const float4* ad1 = (const float4*)(g1_ad + h * C);
        const float4* ad2 = (const float4*)(g2_ad + h * C);
        const float4* as1 = (const float4*)(g1_as + h * C);
        const float4* as2 = (const float4*)(g2_as + h * C);
        float a1 = 0.f, a2 = 0.f, s1 = 0.f, s2 = 0.f;
        #pragma unroll 4
        for (int q = 0; q < 32; q++) {
            float4 x, y;
            x = wd1[q]; y = ad1[q];
            a1 += x.x * y.x + x.y * y.y + x.z * y.z + x.w * y.w;
            x = wd2[q]; y = ad2[q];
            a2 += x.x * y.x + x.y * y.y + x.z * y.z + x.w * y.w;
            x = ws1[q]; y = as1[q];
            s1 += x.x * y.x + x.y * y.y + x.z * y.z + x.w * y.w;
            x = ws2[q]; y = as2[q];
            s2 += x.x * y.x + x.y * y.y + x.z * y.z + x.w * y.w;
        }
        stats[676 + t] = a1;
        stats[932 + t] = a2;
        stats[1200 + t] = s1;
        stats[1456 + t] = s2;
        vd1s[t] = a1;
        vd2s[t] = a2;
    }
    __syncthreads();
    {
        int k = t >> 1, h = t & 1;
        const float4* ws1p = (const float4*)(g1_ws + k * HC + h * C);
        float t0 = 0.f, t1 = 0.f;
        #pragma unroll 4
        for (int q = 0; q < 32; q++) {
            float4 wv = ws1p[q];
            int c = q * 4;
            t0 += wv.x * vd2s[(c + 0) * 2 + 0] + wv.y * vd2s[(c + 1) * 2 + 0]
                + wv.z * vd2s[(c + 2) * 2 + 0] + wv.w * vd2s[(c + 3) * 2 + 0];
            t1 += wv.x * vd2s[(c + 0) * 2 + 1] + wv.y * vd2s[(c + 1) * 2 + 1]
                + wv.z * vd2s[(c + 2) * 2 + 1] + wv.w * vd2s[(c + 3) * 2 + 1];
        }
        stats[1712 + t * 2 + 0] = t0;
        stats[1712 + t * 2 + 1] = t1;
    }
    if (t < 2) {
        float cb = 0.f;
        for (int k = 0; k < C; k++) cb += g1b[k] * vd2s[k * 2 + t];
        stats[1188 + t] = cb;
    }
    // folded r0 vectors: fv[k][h4] = sum_c s[c]*W[k][c]*vd{1,2}[c][h]
    if (t < 80) {
        int k = t >> 2, h4 = t & 3, h = h4 & 1;
        const float* vs = (h4 < 2) ? vd1s : vd2s;
        float acc = 0.f;
        for (int c = 0; c < C; c++) acc += sS[c] * Wm[k * C + c] * vs[c * 2 + h];
        stats[2240 + t] = acc;
    } else if (t < 84) {
        int h4 = t - 80, h = h4 & 1;
        const float* vs = (h4 < 2) ? vd1s : vd2s;
        float acc = 0.f;
        for (int c = 0; c < C; c++) acc += sSh[c] * vs[c * 2 + h];
        stats[2320 + h4] = acc;
    }
}

// ---------------- K_feat: fused r0f GEMV + ingredient psi + user hs MFMA ----------
// blocks [0,R0B): a_d/advd GEMV; [R0B,R0B+IB): ing; [R0B+IB, +HB): user hs
__global__ __launch_bounds__(256) void k_feat(
    const float* __restrict__ x, int NR, int R0B, int IB,
    const float* __restrict__ ing_table, const int* __restrict__ ing_ids, int NI,
    const float* __restrict__ user_table, const int* __restrict__ user_ids, int NU,
    const u16* __restrict__ wsp, const float* __restrict__ stats,
    float* __restrict__ a_d, float* __restrict__ advd,
    float* __restrict__ a_s1, float* __restrict__ psi,
    u16* __restrict__ hs16, float* __restrict__ a_s2)
{
    __shared__ float fv[84];
    __shared__ float u1s[256];
    __shared__ float Ts[512];
    __shared__ __align__(16) u16 A[32 * 136];
    __shared__ float u2s[256];
    int t = threadIdx.x;
    int bid = blockIdx.x;
    if (bid < R0B) {
        // ---- r0f role: [NR,20]x[20,4] GEMV, direct vector loads ----
        if (t < 84) fv[t] = stats[2240 + t];
        __syncthreads();
        int r = bid * 256 + t;
        if (r < NR) {
            const float4* xp = (const float4*)(x + (size_t)r * DIN);   // 80B rows, 16B aligned
            float4 v0 = xp[0], v1 = xp[1], v2 = xp[2], v3 = xp[3], v4 = xp[4];
            float xv[20] = {v0.x, v0.y, v0.z, v0.w, v1.x, v1.y, v1.z, v1.w,
                            v2.x, v2.y, v2.z, v2.w, v3.x, v3.y, v3.z, v3.w,
                            v4.x, v4.y, v4.z, v4.w};
            float a0 = 0.f, a1 = 0.f, b0 = 0.f, b1 = 0.f;
            #pragma unroll
            for (int k = 0; k < DIN; k++) {
                float xvk = xv[k];
                a0 += xvk * fv[k * 4 + 0];
                a1 += xvk * fv[k * 4 + 1];
                b0 += xvk * fv[k * 4 + 2];
                b1 += xvk * fv[k * 4 + 3];
            }
            ((float2*)a_d)[r]  = make_float2(a0 + fv[80], a1 + fv[81]);
            ((float2*)advd)[r] = make_float2(b0 + fv[82], b1 + fv[83]);
        }
        return;
    }
    if (bid < R0B + IB) {
        // ---- ingredient role ----
        u1s[t] = stats[1200 + t];
        Ts[t] = stats[1712 + t];
        Ts[256 + t] = stats[1968 + t];
        __syncthreads();
        int r = t >> 3, cg = t & 7;
        int row = (bid - R0B) * 32 + r;
        float as0 = 0.f, as1 = 0.f, p00 = 0.f, p01 = 0.f, p10 = 0.f, p11 = 0.f;
        if (row < NI) {
            const float* xp = ing_table + (size_t)ing_ids[row] * C + cg * 16;
            #pragma unroll
            for (int q = 0; q < 4; q++) {
                float4 v = ((const float4*)xp)[q];
                float xvv[4] = {v.x, v.y, v.z, v.w};
                #pragma unroll
                for (int jj = 0; jj < 4; jj++) {
                    int k = cg * 16 + q * 4 + jj;
                    float xx = xvv[jj];
                    as0 += xx * u1s[k * 2 + 0];
                    as1 += xx * u1s[k * 2 + 1];
                    p00 += xx * Ts[k * 4 + 0];
                    p01 += xx * Ts[k * 4 + 1];
                    p10 += xx * Ts[k * 4 + 2];
                    p11 += xx * Ts[k * 4 + 3];
                }
            }
        }
        #pragma unroll
        for (int m = 1; m <= 4; m <<= 1) {
            as0 += __shfl_xor(as0, m); as1 += __shfl_xor(as1, m);
            p00 += __shfl_xor(p00, m); p01 += __shfl_xor(p01, m);
            p10 += __shfl_xor(p10, m); p11 += __shfl_xor(p11, m);
        }
        if (cg == 0 && row < NI) {
            ((float2*)a_s1)[row] = make_float2(as0, as1);
            float4 pv; pv.x = p00; pv.y = p01; pv.z = p10; pv.w = p11;
            ((float4*)psi)[row] = pv;
        }
        return;
    }
    // ---- user hs MFMA role ----
    u2s[t] = stats[1456 + t];
    int rowBase = (bid - R0B - IB) * 32;
    int r = t >> 3, cg = t & 7;
    int row = rowBase + r;
    float xv[16];
    if (row < NU) {
        const float* xp = user_table + (size_t)user_ids[row] * C + cg * 16;
        #pragma unroll
        for (int q = 0; q < 4; q++) {
            float4 v = ((const float4*)xp)[q];
            xv[q * 4 + 0] = v.x; xv[q * 4 + 1] = v.y;
            xv[q * 4 + 2] = v.z; xv[q * 4 + 3] = v.w;
        }
    } else {
        #pragma unroll
        for (int q = 0; q < 16; q++) xv[q] = 0.f;
    }
    float ss = 0.f;
    #pragma unroll
    for (int q = 0; q < 16; q++) ss += xv[q] * xv[q];
    #pragma unroll
    for (int m = 1; m <= 4; m <<= 1) ss += __shfl_xor(ss, m);
    float nn = sqrtf(ss);
    float f = (nn > 1.f) ? 1.f / (nn + 1e-7f) : 1.f;
    float as0 = 0.f, as1 = 0.f;
    #pragma unroll
    for (int q = 0; q < 16; q++) {
        xv[q] *= f;
        int k = cg * 16 + q;
        as0 += xv[q] * u2s[k * 2 + 0];
        as1 += xv[q] * u2s[k * 2 + 1];
    }
    #pragma unroll
    for (int m = 1; m <= 4; m <<= 1) {
        as0 += __shfl_xor(as0, m); as1 += __shfl_xor(as1, m);
    }
    if (cg == 0 && row < NU) ((float2*)a_s2)[row] = make_float2(as0, as1);
    {
        union { u16 h[16]; uint4 u4[2]; } pk;
        #pragma unroll
        for (int q = 0; q < 16; q++) pk.h[q] = f2bf_rne(xv[q]);
        uint4* dst = (uint4*)&A[r * 136 + cg * 16];
        dst[0] = pk.u4[0];
        dst[1] = pk.u4[1];
    }
    __syncthreads();
    int w = t >> 6, l = t & 63;
    int m15 = l & 15, q4 = l >> 4;
    bf16x8 afrag[2][4];
    #pragma unroll
    for (int mt = 0; mt < 2; mt++)
        #pragma unroll
        for (int kb = 0; kb < 4; kb++)
            afrag[mt][kb] = *(const bf16x8*)&A[(mt * 16 + m15) * 136 + kb * 32 + q4 * 8];
    f32x4 acc[2][4];
    #pragma unroll
    for (int mt = 0; mt < 2; mt++)
        #pragma unroll
        for (int i = 0; i < 4; i++) acc[mt][i] = (f32x4){0.f, 0.f, 0.f, 0.f};
    #pragma unroll
    for (int kb = 0; kb < 4; kb++) {
        #pragma unroll
        for (int i = 0; i < 4; i++) {
            int nt = w * 4 + i;
            bf16x8 bfrag = *(const bf16x8*)&wsp[((nt * 4 + kb) * 64 + l) * 8];
            acc[0][i] = __builtin_amdgcn_mfma_f32_16x16x32_bf16(afrag[0][kb], bfrag, acc[0][i], 0, 0, 0);
            acc[1][i] = __builtin_amdgcn_mfma_f32_16x16x32_bf16(afrag[1][kb], bfrag, acc[1][i], 0, 0, 0);
        }
    }
    #pragma unroll
    for (int mt = 0; mt < 2; mt++) {
        #pragma unroll
        for (int i = 0; i < 4; i++) {
            int col = (w * 4 + i) * 16 + m15;
            #pragma unroll
            for (int rr = 0; rr < 4; rr++) {
                int rw = rowBase + mt * 16 + q4 * 4 + rr;
                if (rw < NU) hs16[(size_t)rw * HC + col] = f2bf_rne(acc[mt][i][rr]);
            }
        }
    }
}

// A2: local counting sort by bucket, contiguous run writes of packed (key,src)
__global__ __launch_bounds__(256) void kA2(const int* __restrict__ src1, const int* __restrict__ dst1,
    const int* __restrict__ src2, const int* __restrict__ dst2,
    int E1, int L1, int E2, int L2, int NR, int NB,
    u32* __restrict__ gcur, u64* __restrict__ pairs)
{
    __shared__ u64 ldsE[EB2];
    __shared__ u64 ldsS[EB2];
    __shared__ u32 cntA[512], cntB[512], offL[512], tmp[256];
    __shared__ u32 gbase[MAXNB];
    int t = threadIdx.x;
    for (int i = t; i < 512; i += 256) { cntA[i] = 0; cntB[i] = 0; }
    __syncthreads();
    int T1 = E1 + L1, T = T1 + E2 + L2;
    int base = blockIdx.x * EB2;
    int nE = T - base; if (nE > EB2) nE = EB2;
    for (int j = t; j < nE; j += 256) {
        int s, key;
        edge_at(base + j, src1, dst1, src2, dst2, E1, T1, E2, NR, s, key);
        ldsE[j] = ((u64)(u32)key << 32) | (u32)s;
        atomicAdd(&cntA[key >> 9], 1u);
    }
    __syncthreads();
    scan512(cntA, offL, tmp);
    for (int b = t; b < NB; b += 256) {
        u32 c = cntA[b];
        gbase[b] = c ? atomicAdd(&gcur[b], c) : 0u;
    }
    __syncthreads();
    for (int j = t; j < nE; j += 256) {
        u64 e = ldsE[j];
        u32 b = ((u32)(e >> 32)) >> 9;
        u32 r = atomicAdd(&cntB[b], 1u);
        ldsS[offL[b] + r] = e;
    }
    __syncthreads();
    for (int j = t; j < nE; j += 256) {
        u64 e = ldsS[j];
        u32 b = ((u32)(e >> 32)) >> 9;
        pairs[gbase[b] + ((u32)j - offL[b])] = e;
    }
}

// B: per-bucket fine sort -> off[] + sorted[] (sequential writes)
__global__ __launch_bounds__(256) void kB(const u64* __restrict__ pairs,
    const u32* __restrict__ bucketBase, int n2,
    int* __restrict__ off, int* __restrict__ sorted)
{
    __shared__ u32 cntA[512], cntB[512], offL[512], tmp[256];
    __shared__ u32 ldsS[8192];
    int b = blockIdx.x;
    int t = threadIdx.x;
    u32 beg = bucketBase[b], end = bucketBase[b + 1];
    int dstBase = b << 9;
    for (int i = t; i < 512; i += 256) { cntA[i] = 0; cntB[i] = 0; }
    __syncthreads();
    for (u32 j = beg + t; j < end; j += 256) {
        u32 key = (u32)(pairs[j] >> 32);
        atomicAdd(&cntA[key - dstBase], 1u);
    }
    __syncthreads();
    scan512(cntA, offL, tmp);
    for (int d = t; d < 512; d += 256) {
        int gk = dstBase + d;
        if (gk < n2) off[gk] = (int)(beg + offL[d]);
    }
    u32 cnt = end - beg;
    bool fast = cnt <= 8192u;
    __syncthreads();
    for (u32 j = beg + t; j < end; j += 256) {
        u64 e = pairs[j];
        u32 d = (u32)(e >> 32) - dstBase;
        u32 r = atomicAdd(&cntB[d], 1u);
        u32 pos = offL[d] + r;
        if (fast) ldsS[pos] = (u32)e;
        else sorted[beg + pos] = (int)(u32)e;
    }
    __syncthreads();
    if (fast) {
        for (u32 j = t; j < cnt; j += 256) sorted[beg + j] = (int)ldsS[j];
    }
}

// ---------------- GAT1 agg: 16B-per-edge psi aggregation (wave per dst) -----------
__global__ __launch_bounds__(256) void k_agg_lin(const int* __restrict__ off, const int* __restrict__ sorted,
    const float* __restrict__ a_s, const float* __restrict__ psi,
    const float* __restrict__ a_d, const float* __restrict__ advd,
    const float* __restrict__ cb, int NR, float* __restrict__ a_d_out)
{
    int wave = threadIdx.x >> 6, lane = threadIdx.x & 63;
    int d = blockIdx.x * 4 + wave;
    if (d >= NR) return;
    int beg = off[d], end = off[d + 1];
    float ad0 = a_d[d * 2 + 0], ad1 = a_d[d * 2 + 1];
    float w0s = 0.f, w1s = 0.f, a00 = 0.f, a01 = 0.f, a10 = 0.f, a11 = 0.f;
    for (int j = beg + lane; j < end; j += 64) {
        int s = sorted[j];
        float2 as = ((const float2*)a_s)[s];
        float e0 = as.x + ad0; e0 = (e0 >= 0.f) ? e0 : 0.2f * e0;
        float e1 = as.y + ad1; e1 = (e1 >= 0.f) ? e1 : 0.2f * e1;
        float x0 = __expf(e0), x1 = __expf(e1);
        float4 p = ((const float4*)psi)[s];
        w0s += x0; w1s += x1;
        a00 += x0 * p.x; a01 += x0 * p.y;
        a10 += x1 * p.z; a11 += x1 * p.w;
    }
    #pragma unroll
    for (int o = 32; o; o >>= 1) {
        w0s += __shfl_down(w0s, o); w1s += __shfl_down(w1s, o);
        a00 += __shfl_down(a00, o); a01 += __shfl_down(a01, o);
        a10 += __shfl_down(a10, o); a11 += __shfl_down(a11, o);
    }
    if (lane == 0) {
        float inv0 = 1.f / (w0s + 1e-16f), inv1 = 1.f / (w1s + 1e-16f);
        a_d_out[d * 2 + 0] = advd[d * 2 + 0] + cb[0] + 0.5f * (a00 * inv0 + a10 * inv1);
        a_d_out[d * 2 + 1] = advd[d * 2 + 1] + cb[1] + 0.5f * (a01 * inv0 + a11 * inv1);
    }
}

// ---------------- GAT2 agg: one edge per wave-step, full 512B row per load --------
// Lane l owns 4 channels of head (l>>5). Batch of 32 edges: half-wave j loads edge
// j's src + a_s and computes exp ONCE per edge per head (lanes 0-31: head0 weight,
// lanes 32-63: head1 weight). Inner loop: 2 shuffles + 1 dwordx2 + 4 FMA per edge.
// wsum needs no reduction (replicated per half-wave); head-mean = 1 shfl_xor(32).
__global__ __launch_bounds__(256) void k_agg_gather(const int* __restrict__ off, const int* __restrict__ sorted,
    const float* __restrict__ a_s, const float* __restrict__ a_d,
    const u16* __restrict__ hs16, const float* __restrict__ bias,
    int NR, float* __restrict__ out)
{
    int wave = threadIdx.x >> 6, lane = threadIdx.x & 63;
    int d = blockIdx.x * 4 + wave;
    if (d >= NR) return;
    int beg = off[d], end = off[d + 1];
    int head = lane >> 5;              // 0/1
    int q = lane & 31;                 // 4-channel group within head
    u32 laneoff = (u32)(head * 256 + q * 8);   // byte offset within 512B row
    int hsel = lane & 32;              // +32 for head-1 weight shuffle
    float adh = a_d[d * 2 + head];
    float wsum = 0.f;
    float acc0 = 0.f, acc1 = 0.f, acc2 = 0.f, acc3 = 0.f;
    const char* hbase = (const char*)hs16;

    for (int base = beg; base < end; base += 32) {
        int rem = end - base; if (rem > 32) rem = 32;
        int j = q; if (j >= rem) j = rem - 1;
        int sp = sorted[base + j];
        u32 boff = ((u32)sp) << 9;               // *HC*2 bytes
        float asv = a_s[sp * 2 + head];
        float ee = asv + adh; ee = (ee >= 0.f) ? ee : 0.2f * ee;
        float wcomb = __expf(ee);                // lanes<32: w0(edge j); lanes>=32: w1(edge j)
        int e = 0;
        for (; e + 4 <= rem; e += 4) {
            u32 b0 = __shfl(boff, e + 0), b1 = __shfl(boff, e + 1);
            u32 b2 = __shfl(boff, e + 2), b3 = __shfl(boff, e + 3);
            uint2 g0 = *(const uint2*)(hbase + (b0 + laneoff));
            uint2 g1 = *(const uint2*)(hbase + (b1 + laneoff));
            uint2 g2 = *(const uint2*)(hbase + (b2 + laneoff));
            uint2 g3 = *(const uint2*)(hbase + (b3 + laneoff));
            float W0 = __shfl(wcomb, hsel + e + 0);
            float W1 = __shfl(wcomb, hsel + e + 1);
            float W2 = __shfl(wcomb, hsel + e + 2);
            float W3 = __shfl(wcomb, hsel + e + 3);
            wsum += (W0 + W1) + (W2 + W3);
            acc0 += W0 * bfbits2f(g0.x & 0xFFFFu);
            acc1 += W0 * __uint_as_float(g0.x & 0xFFFF0000u);
            acc2 += W0 * bfbits2f(g0.y & 0xFFFFu);
            acc3 += W0 * __uint_as_float(g0.y & 0xFFFF0000u);
            acc0 += W1 * bfbits2f(g1.x & 0xFFFFu);
            acc1 += W1 * __uint_as_float(g1.x & 0xFFFF0000u);
            acc2 += W1 * bfbits2f(g1.y & 0xFFFFu);
            acc3 += W1 * __uint_as_float(g1.y & 0xFFFF0000u);
            acc0 += W2 * bfbits2f(g2.x & 0xFFFFu);
            acc1 += W2 * __uint_as_float(g2.x & 0xFFFF0000u);
            acc2 += W2 * bfbits2f(g2.y & 0xFFFFu);
            acc3 += W2 * __uint_as_float(g2.y & 0xFFFF0000u);
            acc0 += W3 * bfbits2f(g3.x & 0xFFFFu);
            acc1 += W3 * __uint_as_float(g3.x & 0xFFFF0000u);
            acc2 += W3 * bfbits2f(g3.y & 0xFFFFu);
            acc3 += W3 * __uint_as_float(g3.y & 0xFFFF0000u);
        }
        for (; e < rem; e++) {
            u32 b0 = __shfl(boff, e);
            float W = __shfl(wcomb, hsel + e);
            uint2 g = *(const uint2*)(hbase + (b0 + laneoff));
            wsum += W;
            acc0 += W * bfbits2f(g.x & 0xFFFFu);
            acc1 += W * __uint_as_float(g.x & 0xFFFF0000u);
            acc2 += W * bfbits2f(g.y & 0xFFFFu);
            acc3 += W * __uint_as_float(g.y & 0xFFFF0000u);
        }
    }
    float inv = 1.f / (wsum + 1e-16f);
    float v0 = acc0 * inv, v1 = acc1 * inv, v2 = acc2 * inv, v3 = acc3 * inv;
    v0 = 0.5f * (v0 + __shfl_xor(v0, 32));
    v1 = 0.5f * (v1 + __shfl_xor(v1, 32));
    v2 = 0.5f * (v2 + __shfl_xor(v2, 32));
    v3 = 0.5f * (v3 + __shfl_xor(v3, 32));
    if (lane < 32) {
        float4 bb = ((const float4*)bias)[q];
        float4 o;
        o.x = v0 + bb.x; o.y = v1 + bb.y; o.z = v2 + bb.z; o.w = v3 + bb.w;
        ((float4*)(out + (size_t)d * C))[q] = o;
    }
}

extern "C" void kernel_launch(void* const* d_in, const int* in_sizes, int n_in,
                              void* d_out, int out_size, void* d_ws, size_t ws_size,
                              hipStream_t stream) {
    const int*   user_ids       = (const int*)d_in[0];
    const int*   ingredient_ids = (const int*)d_in[1];
    const float* recipe_x       = (const float*)d_in[2];
    const int*   ing_src        = (const int*)d_in[3];
    const int*   ing_dst        = (const int*)d_in[4];
    const int*   ub_src         = (const int*)d_in[5];
    const int*   ub_dst         = (const int*)d_in[6];
    const float* user_table     = (const float*)d_in[7];
    const float* ing_table      = (const float*)d_in[8];
    const float* W_rl           = (const float*)d_in[9];
    const float* bn_gamma       = (const float*)d_in[11];
    const float* bn_beta        = (const float*)d_in[12];
    const float* g1_ws          = (const float*)d_in[13];
    const float* g1_wd          = (const float*)d_in[14];
    const float* g1_as          = (const float*)d_in[15];
    const float* g1_ad          = (const float*)d_in[16];
    const float* g1_b           = (const float*)d_in[17];
    const float* g2_ws          = (const float*)d_in[18];
    const float* g2_wd          = (const float*)d_in[19];
    const float* g2_as          = (const float*)d_in[20];
    const float* g2_ad          = (const float*)d_in[21];
    const float* g2_b           = (const float*)d_in[22];

    int NU = in_sizes[0];
    int NI = in_sizes[1];
    int NR = in_sizes[2] / DIN;
    int E1 = in_sizes[3];
    int E2 = in_sizes[5];
    int Nmax = (NI > NU) ? NI : NU;
    int L1 = (NI < NR) ? NI : NR;
    int L2 = (NU < NR) ? NU : NR;
    int Etot = E1 + L1 + E2 + L2;
    int n2 = 2 * NR;
    int NB = (n2 + 511) >> 9;

    char* w = (char*)d_ws;
    u16*   hs16  = (u16*)w;    w += (size_t)Nmax * HC * 2;
    float* a_s   = (float*)w;  w += (size_t)Nmax * 2 * 4;
    float* psi   = (float*)w;  w += (size_t)NI * 4 * 4;
    float* a_d   = (float*)w;  w += (size_t)NR * 2 * 4;
    float* advd  = (float*)w;  w += (size_t)NR * 2 * 4;
    float* stats = (float*)w;  w += 2432 * 4;
    u32*   bucketCnt  = (u32*)w; w += MAXNB * 4;     // adjacent to stats: one memset
    u16*   wsp   = (u16*)w;    w += 32768 * 2;
    u32*   bucketBase = (u32*)w; w += (MAXNB + 1) * 4;
    u32*   gcur  = (u32*)w;    w += MAXNB * 4;
    int*   off   = (int*)w;    w += (size_t)(n2 + 1) * 4;
    int*   sorted= (int*)w;    w += (size_t)Etot * 4;
    w = (char*)(((size_t)w + 15) & ~(size_t)15);
    u64*   pairs = (u64*)w;    w += (size_t)Etot * 8;

    // zero stats[0..420) + bucketCnt in one shot (extra stats area is overwritten)
    hipMemsetAsync(stats, 0, (2432 + MAXNB) * 4, stream);

    int SB = (NR + 255) / 256;
    int AB = (Etot + EB1 - 1) / EB1;
    // fused: BN stats + bucket histogram
    k_init<<<SB + AB, 256, 0, stream>>>(recipe_x, NR, stats, SB,
                                        ing_src, ing_dst, ub_src, ub_dst,
                                        E1, L1, E2, L2, NB, bucketCnt);
    // fused: precomp + B-pack + bucket scan
    k_precomp_pack<<<34, 256, 0, stream>>>(stats, W_rl, bn_gamma, bn_beta,
                                           g1_wd, g1_ad, g2_wd, g2_ad,
                                           g1_ws, g1_as, g2_ws, g2_as, g1_b,
                                           1.0f / NR, wsp,
                                           bucketCnt, NB, n2, bucketBase, gcur, off);
    kA2<<<(Etot + EB2 - 1) / EB2, 256, 0, stream>>>(ing_src, ing_dst, ub_src, ub_dst,
                                                    E1, L1, E2, L2, NR, NB, gcur, pairs);
    // fused: r0f GEMV + ingredient psi + user hs MFMA
    int R0B = (NR + 255) / 256;
    int IB  = (NI + 31) / 32;
    int HB  = (NU + 31) / 32;
    k_feat<<<R0B + IB + HB, 256, 0, stream>>>(recipe_x, NR, R0B, IB,
                                              ing_table, ingredient_ids, NI,
                                              user_table, user_ids, NU,
                                              wsp, stats, a_d, advd, a_s, psi,
                                              hs16, a_s);
    kB<<<NB, 256, 0, stream>>>(pairs, bucketBase, n2, off, sorted);
    k_agg_lin<<<(NR + 3) / 4, 256, 0, stream>>>(off, sorted, a_s, psi, a_d, advd,
                                                stats + 1188, NR, a_d);
    k_agg_gather<<<(NR + 3) / 4, 256, 0, stream>>>(off + NR, sorted, a_s, a_d, hs16,
                                                   g2_b, NR, (float*)d_out);
}

// Round 4
// 352.418 us; speedup vs baseline: 1.3583x; 1.0709x over previous
//
#include <hip/hip_runtime.h>
#include <hip/hip_bf16.h>
#include <math.h>

#define DIN 20
#define C 128
#define HC 256
#define EB1 8192
#define EB2 2048
#define MAXNB 400

typedef unsigned short u16;
typedef unsigned int u32;
typedef unsigned long long u64;
typedef __bf16 bf16x8 __attribute__((ext_vector_type(8)));
typedef float f32x4 __attribute__((ext_vector_type(4)));

__device__ __forceinline__ float bfbits2f(unsigned int lo16) {
    return __uint_as_float(lo16 << 16);
}
__device__ __forceinline__ u16 f2bf_rne(float f) {
    unsigned int b = __float_as_uint(f);
    return (u16)((b + 0x7FFFu + ((b >> 16) & 1u)) >> 16);
}

// exclusive scan of cnt[0..511] -> off[0..511]; wave-shuffle scan, 2 barriers total
__device__ __forceinline__ void scan512f(u32* cnt, u32* off, u32* wsum4) {
    int t = threadIdx.x;
    int l = t & 63, w = t >> 6;
    u32 a = cnt[2 * t], b = cnt[2 * t + 1];
    u32 s = a + b;
    u32 isc = s;
    #pragma unroll
    for (int o = 1; o < 64; o <<= 1) {
        u32 n = __shfl_up(isc, o);
        if (l >= o) isc += n;
    }
    if (l == 63) wsum4[w] = isc;
    __syncthreads();
    u32 pre = 0;
    if (w > 0) pre += wsum4[0];
    if (w > 1) pre += wsum4[1];
    if (w > 2) pre += wsum4[2];
    u32 excl = pre + isc - s;
    off[2 * t] = excl;
    off[2 * t + 1] = excl + a;
    __syncthreads();
}

__device__ __forceinline__ void edge_at(int i, const int* s1, const int* d1,
    const int* s2, const int* d2, int E1, int T1, int E2, int NR,
    int& s, int& key)
{
    if (i < T1) {
        if (i < E1) { s = s1[i]; key = d1[i]; }
        else        { s = i - E1; key = i - E1; }
    } else {
        int k = i - T1;
        if (k < E2) { s = s2[k]; key = NR + d2[k]; }
        else        { s = k - E2; key = NR + (k - E2); }
    }
}

// ---------------- K_init: fused BN stats + bucket histogram -----------------------
__global__ __launch_bounds__(256) void k_init(const float* __restrict__ x, int NR,
    float* __restrict__ stats, int SB,
    const int* __restrict__ src1, const int* __restrict__ dst1,
    const int* __restrict__ src2, const int* __restrict__ dst2,
    int E1, int L1, int E2, int L2, int NB, u32* __restrict__ bucketCnt)
{
    __shared__ float L[256][DIN];
    __shared__ u32 cnt[MAXNB];
    int t = threadIdx.x;
    if (blockIdx.x < SB) {
        int r = blockIdx.x * 256 + t;
        if (r < NR) {
            #pragma unroll
            for (int k = 0; k < DIN; k++) L[t][k] = x[r * DIN + k];
        } else {
            #pragma unroll
            for (int k = 0; k < DIN; k++) L[t][k] = 0.f;
        }
        __syncthreads();
        if (t < 210) {
            int p = 0, q = t;
            while (q >= DIN - p) { q -= (DIN - p); p++; }
            q += p;
            float acc = 0.f;
            for (int rr = 0; rr < 256; rr++) acc += L[rr][p] * L[rr][q];
            atomicAdd(&stats[p * DIN + q], acc);
            if (p != q) atomicAdd(&stats[q * DIN + p], acc);
        } else if (t < 230) {
            int k = t - 210;
            float acc = 0.f;
            for (int rr = 0; rr < 256; rr++) acc += L[rr][k];
            atomicAdd(&stats[400 + k], acc);
        }
        return;
    }
    for (int i = t; i < NB; i += 256) cnt[i] = 0;
    __syncthreads();
    int T1 = E1 + L1, T = T1 + E2 + L2;
    int base = (blockIdx.x - SB) * EB1;
    int nE = T - base; if (nE > EB1) nE = EB1;
    for (int j = t; j < nE; j += 256) {
        int s, key;
        edge_at(base + j, src1, dst1, src2, dst2, E1, T1, E2, NR, s, key);
        atomicAdd(&cnt[key >> 9], 1u);
    }
    __syncthreads();
    for (int b = t; b < NB; b += 256) {
        u32 c = cnt[b];
        if (c) atomicAdd(&bucketCnt[b], c);
    }
}

// ---------------- K2: precomp (0) + B-pack (1..32) + bucket scan (33) -------------
__global__ __launch_bounds__(256) void k_precomp_pack(float* __restrict__ stats,
    const float* __restrict__ W,
    const float* __restrict__ gamma, const float* __restrict__ beta,
    const float* __restrict__ g1_wd, const float* __restrict__ g1_ad,
    const float* __restrict__ g2_wd, const float* __restrict__ g2_ad,
    const float* __restrict__ g1_ws, const float* __restrict__ g1_as,
    const float* __restrict__ g2_ws, const float* __restrict__ g2_as,
    const float* __restrict__ g1b, float invN, u16* __restrict__ wsp,
    const u32* __restrict__ bucketCnt, int NB, int n2,
    u32* __restrict__ bucketBase, u32* __restrict__ gcur, int* __restrict__ off)
{
    int t = threadIdx.x;
    if (blockIdx.x == 33) {
        __shared__ u32 cnt[512], offL[512], wsum4[4];
        for (int i = t; i < 512; i += 256) cnt[i] = (i < NB) ? bucketCnt[i] : 0u;
        __syncthreads();
        scan512f(cnt, offL, wsum4);
        for (int i = t; i < NB; i += 256) {
            u32 v = offL[i];
            bucketBase[i] = v;
            gcur[i] = v;
        }
        if (t == 0) {
            u32 total = offL[511] + cnt[511];
            bucketBase[NB] = total;
            off[n2] = (int)total;
        }
        return;
    }
    if (blockIdx.x > 0) {
        int idx0 = ((blockIdx.x - 1) * 256 + t) * 4;
        #pragma unroll
        for (int i = 0; i < 4; i++) {
            int flat = idx0 + i;           // [nt(16)][kb(4)][lane(64)][j(8)]
            int j = flat & 7;
            int lane = (flat >> 3) & 63;
            int kb = (flat >> 9) & 3;
            int nt = flat >> 11;
            int k = kb * 32 + (lane >> 4) * 8 + j;
            int n = nt * 16 + (lane & 15);
            wsp[flat] = f2bf_rne(g2_ws[k * HC + n]);
        }
        return;
    }
    __shared__ float Sm[420];
    __shared__ float Wm[DIN * C];
    __shared__ float vd1s[256];
    __shared__ float vd2s[256];
    __shared__ float sS[128];
    __shared__ float sSh[128];
    for (int i = t; i < 420; i += 256) Sm[i] = stats[i];
    for (int i = t; i < DIN * C; i += 256) Wm[i] = W[i];
    __syncthreads();
    if (t < C) {
        float w[DIN];
        #pragma unroll
        for (int k = 0; k < DIN; k++) w[k] = Wm[k * C + t];
        float mb = 0.f;
        #pragma unroll
        for (int k = 0; k < DIN; k++) mb += Sm[400 + k] * invN * w[k];
        float e2 = 0.f;
        for (int p = 0; p < DIN; p++) {
            float acc2 = 0.f;
            #pragma unroll
            for (int q = 0; q < DIN; q++) acc2 += Sm[p * DIN + q] * w[q];
            e2 += w[p] * acc2;
        }
        e2 *= invN;
        float var = e2 - mb * mb;
        float s = gamma[t] * rsqrtf(var + 1e-5f);
        float sh = beta[t] - s * mb;   // b_rl cancels inside BN
        stats[420 + t] = s;
        stats[548 + t] = sh;
        sS[t] = s;
        sSh[t] = sh;
    }
    {
        int k = t >> 1, h = t & 1;
        const float4* wd1 = (const float4*)(g1_wd + k * HC + h * C);
        const float4* wd2 = (const float4*)(g2_wd + k * HC + h * C);
        const float4* ws1 = (const float4*)(g1_ws + k * HC + h * C);
        const float4* ws2 = (const float4*)(g2_ws + k * HC + h * C);
        const float4* ad1 = (const float4*)(g1_ad + h * C);
        const float4* ad2 = (const float4*)(g2_ad + h * C);
        const float4* as1 = (const float4*)(g1_as + h * C);
        const float4* as2 = (const float4*)(g2_as + h * C);
        float a1 = 0.f, a2 = 0.f, s1 = 0.f, s2 = 0.f;
        #pragma unroll 4
        for (int q = 0; q < 32; q++) {
            float4 x, y;
            x = wd1[q]; y = ad1[q];
            a1 += x.x * y.x + x.y * y.y + x.z * y.z + x.w * y.w;
            x = wd2[q]; y = ad2[q];
            a2 += x.x * y.x + x.y * y.y + x.z * y.z + x.w * y.w;
            x = ws1[q]; y = as1[q];
            s1 += x.x * y.x + x.y * y.y + x.z * y.z + x.w * y.w;
            x = ws2[q]; y = as2[q];
            s2 += x.x * y.x + x.y * y.y + x.z * y.z + x.w * y.w;
        }
        stats[676 + t] = a1;
        stats[932 + t] = a2;
        stats[1200 + t] = s1;
        stats[1456 + t] = s2;
        vd1s[t] = a1;
        vd2s[t] = a2;
    }
    __syncthreads();
    {
        int k = t >> 1, h = t & 1;
        const float4* ws1p = (const float4*)(g1_ws + k * HC + h * C);
        float t0 = 0.f, t1 = 0.f;
        #pragma unroll 4
        for (int q = 0; q < 32; q++) {
            float4 wv = ws1p[q];
            int c = q * 4;
            t0 += wv.x * vd2s[(c + 0) * 2 + 0] + wv.y * vd2s[(c + 1) * 2 + 0]
                + wv.z * vd2s[(c + 2) * 2 + 0] + wv.w * vd2s[(c + 3) * 2 + 0];
            t1 += wv.x * vd2s[(c + 0) * 2 + 1] + wv.y * vd2s[(c + 1) * 2 + 1]
                + wv.z * vd2s[(c + 2) * 2 + 1] + wv.w * vd2s[(c + 3) * 2 + 1];
        }
        stats[1712 + t * 2 + 0] = t0;
        stats[1712 + t * 2 + 1] = t1;
    }
    if (t < 2) {
        float cb = 0.f;
        for (int k = 0; k < C; k++) cb += g1b[k] * vd2s[k * 2 + t];
        stats[1188 + t] = cb;
    }
    if (t < 80) {
        int k = t >> 2, h4 = t & 3, h = h4 & 1;
        const float* vs = (h4 < 2) ? vd1s : vd2s;
        float acc = 0.f;
        for (int c = 0; c < C; c++) acc += sS[c] * Wm[k * C + c] * vs[c * 2 + h];
        stats[2240 + t] = acc;
    } else if (t < 84) {
        int h4 = t - 80, h = h4 & 1;
        const float* vs = (h4 < 2) ? vd1s : vd2s;
        float acc = 0.f;
        for (int c = 0; c < C; c++) acc += sSh[c] * vs[c * 2 + h];
        stats[2320 + h4] = acc;
    }
}

// ---------------- K_feat: fused r0f GEMV + ingredient psi + user hs MFMA ----------
// NOTE: a_si (ingredient) and a_su (user) are now SEPARATE buffers (R3 had them
// aliased -> user role silently clobbered ingredient attention logits).
__global__ __launch_bounds__(256) void k_feat(
    const float* __restrict__ x, int NR, int R0B, int IB,
    const float* __restrict__ ing_table, const int* __restrict__ ing_ids, int NI,
    const float* __restrict__ user_table, const int* __restrict__ user_ids, int NU,
    const u16* __restrict__ wsp, const float* __restrict__ stats,
    float* __restrict__ a_d, float* __restrict__ advd,
    float* __restrict__ a_si, float* __restrict__ psi,
    u16* __restrict__ hs16, float* __restrict__ a_su)
{
    __shared__ float fv[84];
    __shared__ float u1s[256];
    __shared__ float Ts[512];
    __shared__ __align__(16) u16 A[32 * 136];
    __shared__ float u2s[256];
    int t = threadIdx.x;
    int bid = blockIdx.x;
    if (bid < R0B) {
        if (t < 84) fv[t] = stats[2240 + t];
        __syncthreads();
        int r = bid * 256 + t;
        if (r < NR) {
            const float4* xp = (const float4*)(x + (size_t)r * DIN);
            float4 v0 = xp[0], v1 = xp[1], v2 = xp[2], v3 = xp[3], v4 = xp[4];
            float xv[20] = {v0.x, v0.y, v0.z, v0.w, v1.x, v1.y, v1.z, v1.w,
                            v2.x, v2.y, v2.z, v2.w, v3.x, v3.y, v3.z, v3.w,
                            v4.x, v4.y, v4.z, v4.w};
            float a0 = 0.f, a1 = 0.f, b0 = 0.f, b1 = 0.f;
            #pragma unroll
            for (int k = 0; k < DIN; k++) {
                float xvk = xv[k];
                a0 += xvk * fv[k * 4 + 0];
                a1 += xvk * fv[k * 4 + 1];
                b0 += xvk * fv[k * 4 + 2];
                b1 += xvk * fv[k * 4 + 3];
            }
            ((float2*)a_d)[r]  = make_float2(a0 + fv[80], a1 + fv[81]);
            ((float2*)advd)[r] = make_float2(b0 + fv[82], b1 + fv[83]);
        }
        return;
    }
    if (bid < R0B + IB) {
        u1s[t] = stats[1200 + t];
        Ts[t] = stats[1712 + t];
        Ts[256 + t] = stats[1968 + t];
        __syncthreads();
        int r = t >> 3, cg = t & 7;
        int row = (bid - R0B) * 32 + r;
        float as0 = 0.f, as1 = 0.f, p00 = 0.f, p01 = 0.f, p10 = 0.f, p11 = 0.f;
        if (row < NI) {
            const float* xp = ing_table + (size_t)ing_ids[row] * C + cg * 16;
            #pragma unroll
            for (int q = 0; q < 4; q++) {
                float4 v = ((const float4*)xp)[q];
                float xvv[4] = {v.x, v.y, v.z, v.w};
                #pragma unroll
                for (int jj = 0; jj < 4; jj++) {
                    int k = cg * 16 + q * 4 + jj;
                    float xx = xvv[jj];
                    as0 += xx * u1s[k * 2 + 0];
                    as1 += xx * u1s[k * 2 + 1];
                    p00 += xx * Ts[k * 4 + 0];
                    p01 += xx * Ts[k * 4 + 1];
                    p10 += xx * Ts[k * 4 + 2];
                    p11 += xx * Ts[k * 4 + 3];
                }
            }
        }
        #pragma unroll
        for (int m = 1; m <= 4; m <<= 1) {
            as0 += __shfl_xor(as0, m); as1 += __shfl_xor(as1, m);
            p00 += __shfl_xor(p00, m); p01 += __shfl_xor(p01, m);
            p10 += __shfl_xor(p10, m); p11 += __shfl_xor(p11, m);
        }
        if (cg == 0 && row < NI) {
            ((float2*)a_si)[row] = make_float2(as0, as1);
            float4 pv; pv.x = p00; pv.y = p01; pv.z = p10; pv.w = p11;
            ((float4*)psi)[row] = pv;
        }
        return;
    }
    u2s[t] = stats[1456 + t];
    int rowBase = (bid - R0B - IB) * 32;
    int r = t >> 3, cg = t & 7;
    int row = rowBase + r;
    float xv[16];
    if (row < NU) {
        const float* xp = user_table + (size_t)user_ids[row] * C + cg * 16;
        #pragma unroll
        for (int q = 0; q < 4; q++) {
            float4 v = ((const float4*)xp)[q];
            xv[q * 4 + 0] = v.x; xv[q * 4 + 1] = v.y;
            xv[q * 4 + 2] = v.z; xv[q * 4 + 3] = v.w;
        }
    } else {
        #pragma unroll
        for (int q = 0; q < 16; q++) xv[q] = 0.f;
    }
    float ss = 0.f;
    #pragma unroll
    for (int q = 0; q < 16; q++) ss += xv[q] * xv[q];
    #pragma unroll
    for (int m = 1; m <= 4; m <<= 1) ss += __shfl_xor(ss, m);
    float nn = sqrtf(ss);
    float f = (nn > 1.f) ? 1.f / (nn + 1e-7f) : 1.f;
    float as0 = 0.f, as1 = 0.f;
    #pragma unroll
    for (int q = 0; q < 16; q++) {
        xv[q] *= f;
        int k = cg * 16 + q;
        as0 += xv[q] * u2s[k * 2 + 0];
        as1 += xv[q] * u2s[k * 2 + 1];
    }
    #pragma unroll
    for (int m = 1; m <= 4; m <<= 1) {
        as0 += __shfl_xor(as0, m); as1 += __shfl_xor(as1, m);
    }
    if (cg == 0 && row < NU) ((float2*)a_su)[row] = make_float2(as0, as1);
    {
        union { u16 h[16]; uint4 u4[2]; } pk;
        #pragma unroll
        for (int q = 0; q < 16; q++) pk.h[q] = f2bf_rne(xv[q]);
        uint4* dst = (uint4*)&A[r * 136 + cg * 16];
        dst[0] = pk.u4[0];
        dst[1] = pk.u4[1];
    }
    __syncthreads();
    int w = t >> 6, l = t & 63;
    int m15 = l & 15, q4 = l >> 4;
    bf16x8 afrag[2][4];
    #pragma unroll
    for (int mt = 0; mt < 2; mt++)
        #pragma unroll
        for (int kb = 0; kb < 4; kb++)
            afrag[mt][kb] = *(const bf16x8*)&A[(mt * 16 + m15) * 136 + kb * 32 + q4 * 8];
    f32x4 acc[2][4];
    #pragma unroll
    for (int mt = 0; mt < 2; mt++)
        #pragma unroll
        for (int i = 0; i < 4; i++) acc[mt][i] = (f32x4){0.f, 0.f, 0.f, 0.f};
    #pragma unroll
    for (int kb = 0; kb < 4; kb++) {
        #pragma unroll
        for (int i = 0; i < 4; i++) {
            int nt = w * 4 + i;
            bf16x8 bfrag = *(const bf16x8*)&wsp[((nt * 4 + kb) * 64 + l) * 8];
            acc[0][i] = __builtin_amdgcn_mfma_f32_16x16x32_bf16(afrag[0][kb], bfrag, acc[0][i], 0, 0, 0);
            acc[1][i] = __builtin_amdgcn_mfma_f32_16x16x32_bf16(afrag[1][kb], bfrag, acc[1][i], 0, 0, 0);
        }
    }
    #pragma unroll
    for (int mt = 0; mt < 2; mt++) {
        #pragma unroll
        for (int i = 0; i < 4; i++) {
            int col = (w * 4 + i) * 16 + m15;
            #pragma unroll
            for (int rr = 0; rr < 4; rr++) {
                int rw = rowBase + mt * 16 + q4 * 4 + rr;
                if (rw < NU) hs16[(size_t)rw * HC + col] = f2bf_rne(acc[mt][i][rr]);
            }
        }
    }
}

// A2: local counting sort by bucket; EB2=2048 -> 416 blocks, ~40KB LDS, 4 blk/CU
__global__ __launch_bounds__(256) void kA2(const int* __restrict__ src1, const int* __restrict__ dst1,
    const int* __restrict__ src2, const int* __restrict__ dst2,
    int E1, int L1, int E2, int L2, int NR, int NB,
    u32* __restrict__ gcur, u64* __restrict__ pairs)
{
    __shared__ u64 ldsE[EB2];
    __shared__ u64 ldsS[EB2];
    __shared__ u32 cntA[512], cntB[512], offL[512], wsum4[4];
    __shared__ u32 gbase[MAXNB];
    int t = threadIdx.x;
    for (int i = t; i < 512; i += 256) { cntA[i] = 0; cntB[i] = 0; }
    __syncthreads();
    int T1 = E1 + L1, T = T1 + E2 + L2;
    int base = blockIdx.x * EB2;
    int nE = T - base; if (nE > EB2) nE = EB2;
    for (int j = t; j < nE; j += 256) {
        int s, key;
        edge_at(base + j, src1, dst1, src2, dst2, E1, T1, E2, NR, s, key);
        ldsE[j] = ((u64)(u32)key << 32) | (u32)s;
        atomicAdd(&cntA[key >> 9], 1u);
    }
    __syncthreads();
    scan512f(cntA, offL, wsum4);
    for (int b = t; b < NB; b += 256) {
        u32 c = cntA[b];
        gbase[b] = c ? atomicAdd(&gcur[b], c) : 0u;
    }
    __syncthreads();
    for (int j = t; j < nE; j += 256) {
        u64 e = ldsE[j];
        u32 b = ((u32)(e >> 32)) >> 9;
        u32 r = atomicAdd(&cntB[b], 1u);
        ldsS[offL[b] + r] = e;
    }
    __syncthreads();
    for (int j = t; j < nE; j += 256) {
        u64 e = ldsS[j];
        u32 b = ((u32)(e >> 32)) >> 9;
        pairs[gbase[b] + ((u32)j - offL[b])] = e;
    }
}

// B: per-bucket fine sort -> off[] + sorted[]
__global__ __launch_bounds__(256) void kB(const u64* __restrict__ pairs,
    const u32* __restrict__ bucketBase, int n2,
    int* __restrict__ off, int* __restrict__ sorted)
{
    __shared__ u32 cntA[512], cntB[512], offL[512], wsum4[4];
    __shared__ u32 ldsS[8192];
    int b = blockIdx.x;
    int t = threadIdx.x;
    u32 beg = bucketBase[b], end = bucketBase[b + 1];
    int dstBase = b << 9;
    for (int i = t; i < 512; i += 256) { cntA[i] = 0; cntB[i] = 0; }
    __syncthreads();
    for (u32 j = beg + t; j < end; j += 256) {
        u32 key = (u32)(pairs[j] >> 32);
        atomicAdd(&cntA[key - dstBase], 1u);
    }
    __syncthreads();
    scan512f(cntA, offL, wsum4);
    for (int d = t; d < 512; d += 256) {
        int gk = dstBase + d;
        if (gk < n2) off[gk] = (int)(beg + offL[d]);
    }
    u32 cnt = end - beg;
    bool fast = cnt <= 8192u;
    __syncthreads();
    for (u32 j = beg + t; j < end; j += 256) {
        u64 e = pairs[j];
        u32 d = (u32)(e >> 32) - dstBase;
        u32 r = atomicAdd(&cntB[d], 1u);
        u32 pos = offL[d] + r;
        if (fast) ldsS[pos] = (u32)e;
        else sorted[beg + pos] = (int)(u32)e;
    }
    __syncthreads();
    if (fast) {
        for (u32 j = t; j < cnt; j += 256) sorted[beg + j] = (int)ldsS[j];
    }
}

// ---------------- Fused aggregation: GAT1 (psi) then GAT2 (hs16 gather) -----------
// Per wave, dst d: phase 1 computes GAT1 result (a_d2) entirely in registers via
// xor-reduce (all lanes get it), phase 2 runs the bf16 row-gather using it.
__global__ __launch_bounds__(256) void k_agg(const int* __restrict__ off, const int* __restrict__ sorted,
    const float* __restrict__ a_si, const float* __restrict__ psi,
    const float* __restrict__ a_d1, const float* __restrict__ advd,
    const float* __restrict__ cb,
    const float* __restrict__ a_su, const u16* __restrict__ hs16,
    const float* __restrict__ bias, int NR, float* __restrict__ out)
{
    int wave = threadIdx.x >> 6, lane = threadIdx.x & 63;
    int d = blockIdx.x * 4 + wave;
    if (d >= NR) return;
    // ---------- phase 1: GAT1 psi aggregation ----------
    int beg = off[d], end = off[d + 1];
    float ad0 = a_d1[d * 2 + 0], ad1 = a_d1[d * 2 + 1];
    float w0s = 0.f, w1s = 0.f, a00 = 0.f, a01 = 0.f, a10 = 0.f, a11 = 0.f;
    for (int j = beg + lane; j < end; j += 64) {
        int s = sorted[j];
        float2 as = ((const float2*)a_si)[s];
        float e0 = as.x + ad0; e0 = (e0 >= 0.f) ? e0 : 0.2f * e0;
        float e1 = as.y + ad1; e1 = (e1 >= 0.f) ? e1 : 0.2f * e1;
        float x0 = __expf(e0), x1 = __expf(e1);
        float4 p = ((const float4*)psi)[s];
        w0s += x0; w1s += x1;
        a00 += x0 * p.x; a01 += x0 * p.y;
        a10 += x1 * p.z; a11 += x1 * p.w;
    }
    #pragma unroll
    for (int o = 1; o < 64; o <<= 1) {
        w0s += __shfl_xor(w0s, o); w1s += __shfl_xor(w1s, o);
        a00 += __shfl_xor(a00, o); a01 += __shfl_xor(a01, o);
        a10 += __shfl_xor(a10, o); a11 += __shfl_xor(a11, o);
    }
    float inv0g = 1.f / (w0s + 1e-16f), inv1g = 1.f / (w1s + 1e-16f);
    float r0 = advd[d * 2 + 0] + cb[0] + 0.5f * (a00 * inv0g + a10 * inv1g);
    float r1 = advd[d * 2 + 1] + cb[1] + 0.5f * (a01 * inv0g + a11 * inv1g);
    // ---------- phase 2: GAT2 hs16 row gather ----------
    int beg2 = off[NR + d], end2 = off[NR + d + 1];
    int head = lane >> 5;
    int q = lane & 31;
    u32 laneoff = (u32)(head * 256 + q * 8);
    int hsel = lane & 32;
    float adh = head ? r1 : r0;
    float wsum = 0.f;
    float acc0 = 0.f, acc1 = 0.f, acc2 = 0.f, acc3 = 0.f;
    const char* hbase = (const char*)hs16;

    for (int base = beg2; base < end2; base += 32) {
        int rem = end2 - base; if (rem > 32) rem = 32;
        int j = q; if (j >= rem) j = rem - 1;
        int sp = sorted[base + j];
        u32 boff = ((u32)sp) << 9;
        float asv = a_su[sp * 2 + head];
        float ee = asv + adh; ee = (ee >= 0.f) ? ee : 0.2f * ee;
        float wcomb = __expf(ee);
        int e = 0;
        for (; e + 4 <= rem; e += 4) {
            u32 b0 = __shfl(boff, e + 0), b1 = __shfl(boff, e + 1);
            u32 b2 = __shfl(boff, e + 2), b3 = __shfl(boff, e + 3);
            uint2 g0 = *(const uint2*)(hbase + (b0 + laneoff));
            uint2 g1 = *(const uint2*)(hbase + (b1 + laneoff));
            uint2 g2 = *(const uint2*)(hbase + (b2 + laneoff));
            uint2 g3 = *(const uint2*)(hbase + (b3 + laneoff));
            float W0 = __shfl(wcomb, hsel + e + 0);
            float W1 = __shfl(wcomb, hsel + e + 1);
            float W2 = __shfl(wcomb, hsel + e + 2);
            float W3 = __shfl(wcomb, hsel + e + 3);
            wsum += (W0 + W1) + (W2 + W3);
            acc0 += W0 * bfbits2f(g0.x & 0xFFFFu);
            acc1 += W0 * __uint_as_float(g0.x & 0xFFFF0000u);
            acc2 += W0 * bfbits2f(g0.y & 0xFFFFu);
            acc3 += W0 * __uint_as_float(g0.y & 0xFFFF0000u);
            acc0 += W1 * bfbits2f(g1.x & 0xFFFFu);
            acc1 += W1 * __uint_as_float(g1.x & 0xFFFF0000u);
            acc2 += W1 * bfbits2f(g1.y & 0xFFFFu);
            acc3 += W1 * __uint_as_float(g1.y & 0xFFFF0000u);
            acc0 += W2 * bfbits2f(g2.x & 0xFFFFu);
            acc1 += W2 * __uint_as_float(g2.x & 0xFFFF0000u);
            acc2 += W2 * bfbits2f(g2.y & 0xFFFFu);
            acc3 += W2 * __uint_as_float(g2.y & 0xFFFF0000u);
            acc0 += W3 * bfbits2f(g3.x & 0xFFFFu);
            acc1 += W3 * __uint_as_float(g3.x & 0xFFFF0000u);
            acc2 += W3 * bfbits2f(g3.y & 0xFFFFu);
            acc3 += W3 * __uint_as_float(g3.y & 0xFFFF0000u);
        }
        for (; e < rem; e++) {
            u32 b0 = __shfl(boff, e);
            float W = __shfl(wcomb, hsel + e);
            uint2 g = *(const uint2*)(hbase + (b0 + laneoff));
            wsum += W;
            acc0 += W * bfbits2f(g.x & 0xFFFFu);
            acc1 += W * __uint_as_float(g.x & 0xFFFF0000u);
            acc2 += W * bfbits2f(g.y & 0xFFFFu);
            acc3 += W * __uint_as_float(g.y & 0xFFFF0000u);
        }
    }
    float inv = 1.f / (wsum + 1e-16f);
    float v0 = acc0 * inv, v1 = acc1 * inv, v2 = acc2 * inv, v3 = acc3 * inv;
    v0 = 0.5f * (v0 + __shfl_xor(v0, 32));
    v1 = 0.5f * (v1 + __shfl_xor(v1, 32));
    v2 = 0.5f * (v2 + __shfl_xor(v2, 32));
    v3 = 0.5f * (v3 + __shfl_xor(v3, 32));
    if (lane < 32) {
        float4 bb = ((const float4*)bias)[q];
        float4 o;
        o.x = v0 + bb.x; o.y = v1 + bb.y; o.z = v2 + bb.z; o.w = v3 + bb.w;
        ((float4*)(out + (size_t)d * C))[q] = o;
    }
}

extern "C" void kernel_launch(void* const* d_in, const int* in_sizes, int n_in,
                              void* d_out, int out_size, void* d_ws, size_t ws_size,
                              hipStream_t stream) {
    const int*   user_ids       = (const int*)d_in[0];
    const int*   ingredient_ids = (const int*)d_in[1];
    const float* recipe_x       = (const float*)d_in[2];
    const int*   ing_src        = (const int*)d_in[3];
    const int*   ing_dst        = (const int*)d_in[4];
    const int*   ub_src         = (const int*)d_in[5];
    const int*   ub_dst         = (const int*)d_in[6];
    const float* user_table     = (const float*)d_in[7];
    const float* ing_table      = (const float*)d_in[8];
    const float* W_rl           = (const float*)d_in[9];
    const float* bn_gamma       = (const float*)d_in[11];
    const float* bn_beta        = (const float*)d_in[12];
    const float* g1_ws          = (const float*)d_in[13];
    const float* g1_wd          = (const float*)d_in[14];
    const float* g1_as          = (const float*)d_in[15];
    const float* g1_ad          = (const float*)d_in[16];
    const float* g1_b           = (const float*)d_in[17];
    const float* g2_ws          = (const float*)d_in[18];
    const float* g2_wd          = (const float*)d_in[19];
    const float* g2_as          = (const float*)d_in[20];
    const float* g2_ad          = (const float*)d_in[21];
    const float* g2_b           = (const float*)d_in[22];

    int NU = in_sizes[0];
    int NI = in_sizes[1];
    int NR = in_sizes[2] / DIN;
    int E1 = in_sizes[3];
    int E2 = in_sizes[5];
    int Nmax = (NI > NU) ? NI : NU;
    int L1 = (NI < NR) ? NI : NR;
    int L2 = (NU < NR) ? NU : NR;
    int Etot = E1 + L1 + E2 + L2;
    int n2 = 2 * NR;
    int NB = (n2 + 511) >> 9;

    char* w = (char*)d_ws;
    u16*   hs16  = (u16*)w;    w += (size_t)Nmax * HC * 2;
    float* a_si  = (float*)w;  w += (size_t)NI * 2 * 4;
    float* a_su  = (float*)w;  w += (size_t)NU * 2 * 4;
    float* psi   = (float*)w;  w += (size_t)NI * 4 * 4;
    float* a_d   = (float*)w;  w += (size_t)NR * 2 * 4;
    float* advd  = (float*)w;  w += (size_t)NR * 2 * 4;
    float* stats = (float*)w;  w += 2432 * 4;
    u32*   bucketCnt  = (u32*)w; w += MAXNB * 4;     // adjacent to stats: one memset
    u16*   wsp   = (u16*)w;    w += 32768 * 2;
    u32*   bucketBase = (u32*)w; w += (MAXNB + 1) * 4;
    u32*   gcur  = (u32*)w;    w += MAXNB * 4;
    int*   off   = (int*)w;    w += (size_t)(n2 + 1) * 4;
    int*   sorted= (int*)w;    w += (size_t)Etot * 4;
    w = (char*)(((size_t)w + 15) & ~(size_t)15);
    u64*   pairs = (u64*)w;    w += (size_t)Etot * 8;

    hipMemsetAsync(stats, 0, (2432 + MAXNB) * 4, stream);

    int SB = (NR + 255) / 256;
    int AB = (Etot + EB1 - 1) / EB1;
    k_init<<<SB + AB, 256, 0, stream>>>(recipe_x, NR, stats, SB,
                                        ing_src, ing_dst, ub_src, ub_dst,
                                        E1, L1, E2, L2, NB, bucketCnt);
    k_precomp_pack<<<34, 256, 0, stream>>>(stats, W_rl, bn_gamma, bn_beta,
                                           g1_wd, g1_ad, g2_wd, g2_ad,
                                           g1_ws, g1_as, g2_ws, g2_as, g1_b,
                                           1.0f / NR, wsp,
                                           bucketCnt, NB, n2, bucketBase, gcur, off);
    kA2<<<(Etot + EB2 - 1) / EB2, 256, 0, stream>>>(ing_src, ing_dst, ub_src, ub_dst,
                                                    E1, L1, E2, L2, NR, NB, gcur, pairs);
    int R0B = (NR + 255) / 256;
    int IB  = (NI + 31) / 32;
    int HB  = (NU + 31) / 32;
    k_feat<<<R0B + IB + HB, 256, 0, stream>>>(recipe_x, NR, R0B, IB,
                                              ing_table, ingredient_ids, NI,
                                              user_table, user_ids, NU,
                                              wsp, stats, a_d, advd, a_si, psi,
                                              hs16, a_su);
    kB<<<NB, 256, 0, stream>>>(pairs, bucketBase, n2, off, sorted);
    // fused GAT1 + GAT2 aggregation
    k_agg<<<(NR + 3) / 4, 256, 0, stream>>>(off, sorted, a_si, psi, a_d, advd,
                                            stats + 1188, a_su, hs16, g2_b, NR,
                                            (float*)d_out);
}